// Round 1
// baseline (1818.207 us; speedup 1.0000x reference)
//
#include <hip/hip_runtime.h>

// GCNConv: out = D^-1/2 (A + I) D^-1/2 (x W) + b
// x: [N,256] f32, edge_index: [2,E] int, W: [256,64] f32, b: [64] f32
// out: [N,64] f32

#define IN_F 256
#define OUT_F 64

// --- deg[i] = 1.0 (self loop) ---
__global__ void init_deg_kernel(float* __restrict__ deg, int n) {
    int i = blockIdx.x * blockDim.x + threadIdx.x;
    if (i < n) deg[i] = 1.0f;
}

// --- deg[col[e]] += 1 ---
__global__ void count_deg_kernel(const int* __restrict__ col, float* __restrict__ deg, int E) {
    int e = blockIdx.x * blockDim.x + threadIdx.x;
    if (e < E) atomicAdd(&deg[col[e]], 1.0f);
}

// --- in place: deg -> rsqrt(deg) ---
__global__ void dinv_kernel(float* __restrict__ deg, int n) {
    int i = blockIdx.x * blockDim.x + threadIdx.x;
    if (i < n) deg[i] = rsqrtf(deg[i]);   // deg >= 1 always (self loop)
}

// --- h = x @ W : one wave per row, lane = output feature ---
__global__ void gemm_kernel(const float* __restrict__ x, const float* __restrict__ W,
                            float* __restrict__ h, int n) {
    int row = blockIdx.x * 4 + (threadIdx.x >> 6);
    int f   = threadIdx.x & 63;
    if (row >= n) return;
    const float4* xr = (const float4*)(x + (size_t)row * IN_F);
    float acc = 0.f;
    #pragma unroll 8
    for (int k4 = 0; k4 < IN_F / 4; ++k4) {
        float4 xv = xr[k4];
        int k = k4 * 4;
        acc += xv.x * W[(k + 0) * OUT_F + f];
        acc += xv.y * W[(k + 1) * OUT_F + f];
        acc += xv.z * W[(k + 2) * OUT_F + f];
        acc += xv.w * W[(k + 3) * OUT_F + f];
    }
    h[(size_t)row * OUT_F + f] = acc;
}

// --- out[i] = dinv[i]^2 * h[i] + b  (self-loop term; also zero-inits out) ---
__global__ void out_init_kernel(const float* __restrict__ h, const float* __restrict__ dinv,
                                const float* __restrict__ b, float* __restrict__ out, int n) {
    int gid = blockIdx.x * blockDim.x + threadIdx.x;   // n*16 threads
    int i = gid >> 4, l = gid & 15;
    if (i >= n) return;
    float di = dinv[i];
    float s = di * di;
    float4 hv = ((const float4*)(h + (size_t)i * OUT_F))[l];
    float4 bv = ((const float4*)b)[l];
    float4 o;
    o.x = hv.x * s + bv.x;
    o.y = hv.y * s + bv.y;
    o.z = hv.z * s + bv.z;
    o.w = hv.w * s + bv.w;
    ((float4*)(out + (size_t)i * OUT_F))[l] = o;
}

// --- out[col] += dinv[row]*dinv[col] * h[row], 16 threads per edge ---
__global__ void scatter_kernel(const int* __restrict__ row, const int* __restrict__ col,
                               const float* __restrict__ h, const float* __restrict__ dinv,
                               float* __restrict__ out, int E) {
    long long gid = (long long)blockIdx.x * blockDim.x + threadIdx.x;
    int e = (int)(gid >> 4);
    int l = (int)(gid & 15);
    if (e >= E) return;
    int r = row[e], c = col[e];
    float nrm = dinv[r] * dinv[c];
    float4 hv = ((const float4*)(h + (size_t)r * OUT_F))[l];
    float* o = out + (size_t)c * OUT_F + l * 4;
    atomicAdd(o + 0, hv.x * nrm);
    atomicAdd(o + 1, hv.y * nrm);
    atomicAdd(o + 2, hv.z * nrm);
    atomicAdd(o + 3, hv.w * nrm);
}

extern "C" void kernel_launch(void* const* d_in, const int* in_sizes, int n_in,
                              void* d_out, int out_size, void* d_ws, size_t ws_size,
                              hipStream_t stream) {
    const float* x  = (const float*)d_in[0];
    const int*   ei = (const int*)d_in[1];
    const float* W  = (const float*)d_in[2];
    const float* b  = (const float*)d_in[3];
    float* out = (float*)d_out;

    int n = in_sizes[0] / IN_F;
    int E = in_sizes[1] / 2;
    const int* rowp = ei;       // edge_index[0] = source
    const int* colp = ei + E;   // edge_index[1] = target

    // workspace layout: h [n*64] f32, then dinv [n] f32
    float* h    = (float*)d_ws;
    float* dinv = h + (size_t)n * OUT_F;

    init_deg_kernel<<<(n + 255) / 256, 256, 0, stream>>>(dinv, n);
    count_deg_kernel<<<(E + 255) / 256, 256, 0, stream>>>(colp, dinv, E);
    dinv_kernel<<<(n + 255) / 256, 256, 0, stream>>>(dinv, n);
    gemm_kernel<<<(n + 3) / 4, 256, 0, stream>>>(x, W, h, n);
    out_init_kernel<<<(n * 16 + 255) / 256, 256, 0, stream>>>(h, dinv, b, out, n);
    long long scatter_threads = (long long)E * 16;
    scatter_kernel<<<(int)((scatter_threads + 255) / 256), 256, 0, stream>>>(rowp, colp, h, dinv, out, E);
}

// Round 2
// 689.745 us; speedup vs baseline: 2.6361x; 2.6361x over previous
//
#include <hip/hip_runtime.h>

// GCNConv: out = D^-1/2 (A + I) D^-1/2 (x W) + b
// x: [N,256] f32, edge_index: [2,E] int, W: [256,64] f32, b: [64] f32
// out: [N,64] f32
//
// Strategy: CSR-gather instead of atomic scatter.
//   deg (int atomics) -> exclusive scan -> bucket edges by dest -> per-node gather.

#define IN_F 256
#define OUT_F 64
#define SCAN_THREADS 1024

// --- deg[col[e]] += 1 (int) ---
__global__ void count_deg_kernel(const int* __restrict__ col, int* __restrict__ deg, int E) {
    int e = blockIdx.x * blockDim.x + threadIdx.x;
    if (e < E) atomicAdd(&deg[col[e]], 1);
}

// --- dinv[i] = rsqrt(deg[i] + 1)  (+1 = self loop) ---
__global__ void dinv_kernel(const int* __restrict__ deg, float* __restrict__ dinv, int n) {
    int i = blockIdx.x * blockDim.x + threadIdx.x;
    if (i < n) dinv[i] = rsqrtf((float)(deg[i] + 1));
}

// --- exclusive scan of deg -> start, single block of 1024 threads ---
__global__ void scan_kernel(const int* __restrict__ deg, int* __restrict__ start, int n) {
    __shared__ int lds[SCAN_THREADS];
    int tid = threadIdx.x;
    int per = (n + SCAN_THREADS - 1) / SCAN_THREADS;
    int lo = tid * per;
    int hi = lo + per; if (hi > n) hi = n;
    int s = 0;
    for (int i = lo; i < hi; ++i) s += deg[i];
    lds[tid] = s;
    __syncthreads();
    // Hillis-Steele inclusive scan over thread sums
    for (int d = 1; d < SCAN_THREADS; d <<= 1) {
        int v = (tid >= d) ? lds[tid - d] : 0;
        __syncthreads();
        lds[tid] += v;
        __syncthreads();
    }
    int off = lds[tid] - s;  // exclusive prefix for this thread's chunk
    for (int i = lo; i < hi; ++i) { start[i] = off; off += deg[i]; }
}

// --- bucket[pos] = row[e], pos = cursor[col[e]]++ ---
__global__ void bucket_kernel(const int* __restrict__ row, const int* __restrict__ col,
                              int* __restrict__ cursor, int* __restrict__ bucket, int E) {
    int e = blockIdx.x * blockDim.x + threadIdx.x;
    if (e < E) {
        int pos = atomicAdd(&cursor[col[e]], 1);
        bucket[pos] = row[e];
    }
}

// --- h = x @ W : one wave per 4 rows, lane = output feature ---
__global__ void gemm_kernel(const float* __restrict__ x, const float* __restrict__ W,
                            float* __restrict__ h, int n) {
    int wave = blockIdx.x * 4 + (threadIdx.x >> 6);
    int f    = threadIdx.x & 63;
    int row0 = wave * 4;
    if (row0 >= n) return;
    if (row0 + 4 <= n) {
        const float4* xr0 = (const float4*)(x + (size_t)(row0 + 0) * IN_F);
        const float4* xr1 = (const float4*)(x + (size_t)(row0 + 1) * IN_F);
        const float4* xr2 = (const float4*)(x + (size_t)(row0 + 2) * IN_F);
        const float4* xr3 = (const float4*)(x + (size_t)(row0 + 3) * IN_F);
        float acc0 = 0.f, acc1 = 0.f, acc2 = 0.f, acc3 = 0.f;
        #pragma unroll 4
        for (int k4 = 0; k4 < IN_F / 4; ++k4) {
            int k = k4 * 4;
            float w0 = W[(k + 0) * OUT_F + f];
            float w1 = W[(k + 1) * OUT_F + f];
            float w2 = W[(k + 2) * OUT_F + f];
            float w3 = W[(k + 3) * OUT_F + f];
            float4 a0 = xr0[k4], a1 = xr1[k4], a2 = xr2[k4], a3 = xr3[k4];
            acc0 += a0.x * w0 + a0.y * w1 + a0.z * w2 + a0.w * w3;
            acc1 += a1.x * w0 + a1.y * w1 + a1.z * w2 + a1.w * w3;
            acc2 += a2.x * w0 + a2.y * w1 + a2.z * w2 + a2.w * w3;
            acc3 += a3.x * w0 + a3.y * w1 + a3.z * w2 + a3.w * w3;
        }
        h[(size_t)(row0 + 0) * OUT_F + f] = acc0;
        h[(size_t)(row0 + 1) * OUT_F + f] = acc1;
        h[(size_t)(row0 + 2) * OUT_F + f] = acc2;
        h[(size_t)(row0 + 3) * OUT_F + f] = acc3;
    } else {
        for (int r = row0; r < n; ++r) {
            const float4* xr = (const float4*)(x + (size_t)r * IN_F);
            float acc = 0.f;
            for (int k4 = 0; k4 < IN_F / 4; ++k4) {
                int k = k4 * 4;
                float4 a = xr[k4];
                acc += a.x * W[(k + 0) * OUT_F + f];
                acc += a.y * W[(k + 1) * OUT_F + f];
                acc += a.z * W[(k + 2) * OUT_F + f];
                acc += a.w * W[(k + 3) * OUT_F + f];
            }
            h[(size_t)r * OUT_F + f] = acc;
        }
    }
}

// --- out[c] = dinv[c] * sum_j h[bucket[j]]*dinv[bucket[j]] + dinv[c]^2*h[c] + b ---
__global__ void gather_kernel(const int* __restrict__ start, const int* __restrict__ deg,
                              const int* __restrict__ bucket, const float* __restrict__ h,
                              const float* __restrict__ dinv, const float* __restrict__ b,
                              float* __restrict__ out, int n) {
    int node = blockIdx.x * 4 + (threadIdx.x >> 6);
    int f    = threadIdx.x & 63;
    if (node >= n) return;
    int s0  = start[node];
    int cnt = deg[node];
    float acc = 0.f;
    int j = 0;
    for (; j + 1 < cnt; j += 2) {
        int r0 = bucket[s0 + j];
        int r1 = bucket[s0 + j + 1];
        acc += h[(size_t)r0 * OUT_F + f] * dinv[r0];
        acc += h[(size_t)r1 * OUT_F + f] * dinv[r1];
    }
    if (j < cnt) {
        int r = bucket[s0 + j];
        acc += h[(size_t)r * OUT_F + f] * dinv[r];
    }
    float dc = dinv[node];
    out[(size_t)node * OUT_F + f] = acc * dc + dc * dc * h[(size_t)node * OUT_F + f] + b[f];
}

extern "C" void kernel_launch(void* const* d_in, const int* in_sizes, int n_in,
                              void* d_out, int out_size, void* d_ws, size_t ws_size,
                              hipStream_t stream) {
    const float* x  = (const float*)d_in[0];
    const int*   ei = (const int*)d_in[1];
    const float* W  = (const float*)d_in[2];
    const float* b  = (const float*)d_in[3];
    float* out = (float*)d_out;

    int n = in_sizes[0] / IN_F;
    int E = in_sizes[1] / 2;
    const int* rowp = ei;       // edge_index[0] = source
    const int* colp = ei + E;   // edge_index[1] = target

    // workspace layout
    float* h      = (float*)d_ws;                    // n*64 f32 = 25.6 MB
    int*   bucket = (int*)(h + (size_t)n * OUT_F);   // E int   =  6.4 MB
    int*   deg    = bucket + E;                      // n int
    float* dinv   = (float*)(deg + n);               // n f32
    int*   start  = (int*)(dinv + n);                // n int
    int*   cursor = start + n;                       // n int

    hipMemsetAsync(deg, 0, (size_t)n * sizeof(int), stream);
    count_deg_kernel<<<(E + 255) / 256, 256, 0, stream>>>(colp, deg, E);
    dinv_kernel<<<(n + 255) / 256, 256, 0, stream>>>(deg, dinv, n);
    scan_kernel<<<1, SCAN_THREADS, 0, stream>>>(deg, start, n);
    hipMemcpyAsync(cursor, start, (size_t)n * sizeof(int), hipMemcpyDeviceToDevice, stream);
    bucket_kernel<<<(E + 255) / 256, 256, 0, stream>>>(rowp, colp, cursor, bucket, E);
    gemm_kernel<<<(n + 15) / 16, 256, 0, stream>>>(x, W, h, n);
    gather_kernel<<<(n + 3) / 4, 256, 0, stream>>>(start, deg, bucket, h, dinv, b, out, n);
}

// Round 3
// 606.849 us; speedup vs baseline: 2.9961x; 1.1366x over previous
//
#include <hip/hip_runtime.h>

// GCNConv: out = D^-1/2 (A + I) D^-1/2 (x W) + b
// x: [N,256] f32, edge_index: [2,E] int, W: [256,64] f32, b: [64] f32
// out: [N,64] f32
//
// CSR-gather aggregation + register-tiled fp32 GEMM (8 rows x 4 cols / thread).

#define IN_F 256
#define OUT_F 64
#define SCAN_THREADS 1024
#define ROWS_PER_BLOCK 128

// --- deg[col[e]] += 1 (int) ---
__global__ void count_deg_kernel(const int* __restrict__ col, int* __restrict__ deg, int E) {
    int e = blockIdx.x * blockDim.x + threadIdx.x;
    if (e < E) atomicAdd(&deg[col[e]], 1);
}

// --- dinv[i] = rsqrt(deg[i] + 1)  (+1 = self loop) ---
__global__ void dinv_kernel(const int* __restrict__ deg, float* __restrict__ dinv, int n) {
    int i = blockIdx.x * blockDim.x + threadIdx.x;
    if (i < n) dinv[i] = rsqrtf((float)(deg[i] + 1));
}

// --- exclusive scan of deg -> start, single block of 1024 threads ---
__global__ void scan_kernel(const int* __restrict__ deg, int* __restrict__ start, int n) {
    __shared__ int lds[SCAN_THREADS];
    int tid = threadIdx.x;
    int per = (n + SCAN_THREADS - 1) / SCAN_THREADS;
    int lo = tid * per;
    int hi = lo + per; if (hi > n) hi = n;
    int s = 0;
    for (int i = lo; i < hi; ++i) s += deg[i];
    lds[tid] = s;
    __syncthreads();
    for (int d = 1; d < SCAN_THREADS; d <<= 1) {
        int v = (tid >= d) ? lds[tid - d] : 0;
        __syncthreads();
        lds[tid] += v;
        __syncthreads();
    }
    int off = lds[tid] - s;
    for (int i = lo; i < hi; ++i) { start[i] = off; off += deg[i]; }
}

// --- bucket[pos] = row[e], pos = cursor[col[e]]++ ---
__global__ void bucket_kernel(const int* __restrict__ row, const int* __restrict__ col,
                              int* __restrict__ cursor, int* __restrict__ bucket, int E) {
    int e = blockIdx.x * blockDim.x + threadIdx.x;
    if (e < E) {
        int pos = atomicAdd(&cursor[col[e]], 1);
        bucket[pos] = row[e];
    }
}

// --- h = x @ W : register-tiled, 8 rows x 4 cols per thread ---
__global__ __launch_bounds__(256) void gemm_kernel(const float* __restrict__ x,
                                                   const float* __restrict__ W,
                                                   float* __restrict__ h, int n) {
    int tc = threadIdx.x & 15;   // col group: cols tc*4 .. tc*4+3
    int tr = threadIdx.x >> 4;   // row group: 8 rows
    int row0 = blockIdx.x * ROWS_PER_BLOCK + tr * 8;

    const float4* Wv = (const float4*)W;  // [256][16] float4

    float4 acc[8];
    #pragma unroll
    for (int i = 0; i < 8; ++i) acc[i] = make_float4(0.f, 0.f, 0.f, 0.f);

    const float4* xr[8];
    #pragma unroll
    for (int i = 0; i < 8; ++i) {
        int r = row0 + i;
        if (r > n - 1) r = n - 1;      // clamp for tail block (reads only)
        xr[i] = (const float4*)(x + (size_t)r * IN_F);
    }

    #pragma unroll 2
    for (int k4 = 0; k4 < IN_F / 4; ++k4) {
        float4 w0 = Wv[(k4 * 4 + 0) * 16 + tc];
        float4 w1 = Wv[(k4 * 4 + 1) * 16 + tc];
        float4 w2 = Wv[(k4 * 4 + 2) * 16 + tc];
        float4 w3 = Wv[(k4 * 4 + 3) * 16 + tc];
        #pragma unroll
        for (int i = 0; i < 8; ++i) {
            float4 xv = xr[i][k4];
            acc[i].x += xv.x * w0.x + xv.y * w1.x + xv.z * w2.x + xv.w * w3.x;
            acc[i].y += xv.x * w0.y + xv.y * w1.y + xv.z * w2.y + xv.w * w3.y;
            acc[i].z += xv.x * w0.z + xv.y * w1.z + xv.z * w2.z + xv.w * w3.z;
            acc[i].w += xv.x * w0.w + xv.y * w1.w + xv.z * w2.w + xv.w * w3.w;
        }
    }

    #pragma unroll
    for (int i = 0; i < 8; ++i) {
        int r = row0 + i;
        if (r < n) ((float4*)(h + (size_t)r * OUT_F))[tc] = acc[i];
    }
}

// --- out[c] = dinv[c] * sum_j h[bucket[j]]*dinv[bucket[j]] + dinv[c]^2*h[c] + b ---
__global__ void gather_kernel(const int* __restrict__ start, const int* __restrict__ deg,
                              const int* __restrict__ bucket, const float* __restrict__ h,
                              const float* __restrict__ dinv, const float* __restrict__ b,
                              float* __restrict__ out, int n) {
    int node = blockIdx.x * 4 + (threadIdx.x >> 6);
    int f    = threadIdx.x & 63;
    if (node >= n) return;
    int s0  = start[node];
    int cnt = deg[node];
    float acc = 0.f;
    int j = 0;
    for (; j + 1 < cnt; j += 2) {
        int r0 = bucket[s0 + j];
        int r1 = bucket[s0 + j + 1];
        acc += h[(size_t)r0 * OUT_F + f] * dinv[r0];
        acc += h[(size_t)r1 * OUT_F + f] * dinv[r1];
    }
    if (j < cnt) {
        int r = bucket[s0 + j];
        acc += h[(size_t)r * OUT_F + f] * dinv[r];
    }
    float dc = dinv[node];
    out[(size_t)node * OUT_F + f] = acc * dc + dc * dc * h[(size_t)node * OUT_F + f] + b[f];
}

extern "C" void kernel_launch(void* const* d_in, const int* in_sizes, int n_in,
                              void* d_out, int out_size, void* d_ws, size_t ws_size,
                              hipStream_t stream) {
    const float* x  = (const float*)d_in[0];
    const int*   ei = (const int*)d_in[1];
    const float* W  = (const float*)d_in[2];
    const float* b  = (const float*)d_in[3];
    float* out = (float*)d_out;

    int n = in_sizes[0] / IN_F;
    int E = in_sizes[1] / 2;
    const int* rowp = ei;       // edge_index[0] = source
    const int* colp = ei + E;   // edge_index[1] = target

    // workspace layout
    float* h      = (float*)d_ws;                    // n*64 f32 = 25.6 MB
    int*   bucket = (int*)(h + (size_t)n * OUT_F);   // E int   =  6.4 MB
    int*   deg    = bucket + E;                      // n int
    float* dinv   = (float*)(deg + n);               // n f32
    int*   start  = (int*)(dinv + n);                // n int
    int*   cursor = start + n;                       // n int

    hipMemsetAsync(deg, 0, (size_t)n * sizeof(int), stream);
    count_deg_kernel<<<(E + 255) / 256, 256, 0, stream>>>(colp, deg, E);
    dinv_kernel<<<(n + 255) / 256, 256, 0, stream>>>(deg, dinv, n);
    scan_kernel<<<1, SCAN_THREADS, 0, stream>>>(deg, start, n);
    hipMemcpyAsync(cursor, start, (size_t)n * sizeof(int), hipMemcpyDeviceToDevice, stream);
    bucket_kernel<<<(E + 255) / 256, 256, 0, stream>>>(rowp, colp, cursor, bucket, E);
    gemm_kernel<<<(n + ROWS_PER_BLOCK - 1) / ROWS_PER_BLOCK, 256, 0, stream>>>(x, W, h, n);
    gather_kernel<<<(n + 3) / 4, 256, 0, stream>>>(start, deg, bucket, h, dinv, b, out, n);
}

// Round 4
// 379.540 us; speedup vs baseline: 4.7906x; 1.5989x over previous
//
#include <hip/hip_runtime.h>

// GCNConv: out = D^-1/2 (A + I) D^-1/2 (x W) + b
// x: [N,256] f32, edge_index: [2,E] int, W: [256,64] f32, b: [64] f32
// out: [N,64] f32
//
// CSR-gather aggregation; LDS-staged fp32 GEMM with dinv folded into epilogue.

#define IN_F 256
#define OUT_F 64
#define GR 32            // gemm rows per block
#define XS_STRIDE 65     // row stride in float4s (64 data + 1 pad -> distinct banks)

// --- deg[col[e]] += 1 (int) ---
__global__ void count_deg_kernel(const int* __restrict__ col, int* __restrict__ deg, int E) {
    int e = blockIdx.x * blockDim.x + threadIdx.x;
    if (e < E) atomicAdd(&deg[col[e]], 1);
}

// --- dinv[i] = rsqrt(deg[i] + 1)  (+1 = self loop) ---
__global__ void dinv_kernel(const int* __restrict__ deg, float* __restrict__ dinv, int n) {
    int i = blockIdx.x * blockDim.x + threadIdx.x;
    if (i < n) dinv[i] = rsqrtf((float)(deg[i] + 1));
}

// --- scan pass 1: block-local exclusive scan of deg into start; block sum -> bsum ---
__global__ void scan1_kernel(const int* __restrict__ deg, int* __restrict__ start,
                             int* __restrict__ bsum, int n) {
    __shared__ int lds[256];
    int tid = threadIdx.x;
    int i = blockIdx.x * 256 + tid;
    int v = (i < n) ? deg[i] : 0;
    lds[tid] = v;
    __syncthreads();
    for (int d = 1; d < 256; d <<= 1) {
        int t = (tid >= d) ? lds[tid - d] : 0;
        __syncthreads();
        lds[tid] += t;
        __syncthreads();
    }
    if (i < n) start[i] = lds[tid] - v;           // block-local exclusive
    if (tid == 255) bsum[blockIdx.x] = lds[255];  // block total
}

// --- scan pass 2: exclusive scan of bsum (nb <= 512), single block ---
__global__ void scan2_kernel(int* __restrict__ bsum, int nb) {
    __shared__ int lds[512];
    int tid = threadIdx.x;
    int v = (tid < nb) ? bsum[tid] : 0;
    lds[tid] = v;
    __syncthreads();
    for (int d = 1; d < 512; d <<= 1) {
        int t = (tid >= d) ? lds[tid - d] : 0;
        __syncthreads();
        lds[tid] += t;
        __syncthreads();
    }
    if (tid < nb) bsum[tid] = lds[tid] - v;       // exclusive
}

// --- scan pass 3: start[i] += bsum[block]; cursor[i] = start[i] ---
__global__ void scan3_kernel(int* __restrict__ start, int* __restrict__ cursor,
                             const int* __restrict__ bsum, int n) {
    int i = blockIdx.x * 256 + threadIdx.x;
    if (i < n) {
        int s = start[i] + bsum[blockIdx.x];
        start[i] = s;
        cursor[i] = s;
    }
}

// --- bucket[pos] = row[e], pos = cursor[col[e]]++ ---
__global__ void bucket_kernel(const int* __restrict__ row, const int* __restrict__ col,
                              int* __restrict__ cursor, int* __restrict__ bucket, int E) {
    int e = blockIdx.x * blockDim.x + threadIdx.x;
    if (e < E) {
        int pos = atomicAdd(&cursor[col[e]], 1);
        bucket[pos] = row[e];
    }
}

// --- g = dinv[r] * (x @ W)[r] : LDS-staged x tile, 2 rows x 4 cols per thread ---
__global__ __launch_bounds__(256) void gemm_kernel(const float* __restrict__ x,
                                                   const float* __restrict__ W,
                                                   const float* __restrict__ dinv,
                                                   float* __restrict__ g, int n) {
    __shared__ float4 xs[GR * XS_STRIDE];
    int tid = threadIdx.x;
    int row0 = blockIdx.x * GR;

    // stage 32 rows x 64 float4s, coalesced; clamp reads for (non-existent) tail
    const float4* xg = (const float4*)x;
    #pragma unroll
    for (int i = 0; i < GR * (IN_F / 4) / 256; ++i) {   // 8 iters
        int idx = i * 256 + tid;
        int r = idx >> 6;          // 0..31
        int c = idx & 63;          // 0..63
        int grow = row0 + r;
        if (grow > n - 1) grow = n - 1;
        xs[r * XS_STRIDE + c] = xg[(size_t)grow * (IN_F / 4) + c];
    }
    __syncthreads();

    int tc = tid & 15;             // col group: cols tc*4..tc*4+3
    int tr = tid >> 4;             // row group: rows tr*2, tr*2+1
    const float4* Wv = (const float4*)W;
    const float4* xr0 = &xs[(tr * 2 + 0) * XS_STRIDE];
    const float4* xr1 = &xs[(tr * 2 + 1) * XS_STRIDE];

    float4 acc0 = make_float4(0.f, 0.f, 0.f, 0.f);
    float4 acc1 = make_float4(0.f, 0.f, 0.f, 0.f);

    #pragma unroll 4
    for (int k4 = 0; k4 < IN_F / 4; ++k4) {
        float4 w0 = Wv[(k4 * 4 + 0) * 16 + tc];
        float4 w1 = Wv[(k4 * 4 + 1) * 16 + tc];
        float4 w2 = Wv[(k4 * 4 + 2) * 16 + tc];
        float4 w3 = Wv[(k4 * 4 + 3) * 16 + tc];
        float4 a0 = xr0[k4];
        float4 a1 = xr1[k4];
        acc0.x += a0.x * w0.x + a0.y * w1.x + a0.z * w2.x + a0.w * w3.x;
        acc0.y += a0.x * w0.y + a0.y * w1.y + a0.z * w2.y + a0.w * w3.y;
        acc0.z += a0.x * w0.z + a0.y * w1.z + a0.z * w2.z + a0.w * w3.z;
        acc0.w += a0.x * w0.w + a0.y * w1.w + a0.z * w2.w + a0.w * w3.w;
        acc1.x += a1.x * w0.x + a1.y * w1.x + a1.z * w2.x + a1.w * w3.x;
        acc1.y += a1.x * w0.y + a1.y * w1.y + a1.z * w2.y + a1.w * w3.y;
        acc1.z += a1.x * w0.z + a1.y * w1.z + a1.z * w2.z + a1.w * w3.z;
        acc1.w += a1.x * w0.w + a1.y * w1.w + a1.z * w2.w + a1.w * w3.w;
    }

    int r0 = row0 + tr * 2;
    int r1 = r0 + 1;
    if (r0 < n) {
        float d0 = dinv[r0];
        acc0.x *= d0; acc0.y *= d0; acc0.z *= d0; acc0.w *= d0;
        ((float4*)(g + (size_t)r0 * OUT_F))[tc] = acc0;
    }
    if (r1 < n) {
        float d1 = dinv[r1];
        acc1.x *= d1; acc1.y *= d1; acc1.z *= d1; acc1.w *= d1;
        ((float4*)(g + (size_t)r1 * OUT_F))[tc] = acc1;
    }
}

// --- out[c] = dinv[c] * (g[c] + sum_j g[bucket[j]]) + b ---
__global__ void gather_kernel(const int* __restrict__ start, const int* __restrict__ deg,
                              const int* __restrict__ bucket, const float* __restrict__ g,
                              const float* __restrict__ dinv, const float* __restrict__ b,
                              float* __restrict__ out, int n) {
    int node = blockIdx.x * 4 + (threadIdx.x >> 6);
    int f    = threadIdx.x & 63;
    if (node >= n) return;
    int s0  = start[node];
    int cnt = deg[node];
    float acc = 0.f;
    int j = 0;
    for (; j + 4 <= cnt; j += 4) {
        int r0 = bucket[s0 + j + 0];
        int r1 = bucket[s0 + j + 1];
        int r2 = bucket[s0 + j + 2];
        int r3 = bucket[s0 + j + 3];
        float v0 = g[(size_t)r0 * OUT_F + f];
        float v1 = g[(size_t)r1 * OUT_F + f];
        float v2 = g[(size_t)r2 * OUT_F + f];
        float v3 = g[(size_t)r3 * OUT_F + f];
        acc += v0 + v1 + v2 + v3;
    }
    for (; j < cnt; ++j) {
        int r = bucket[s0 + j];
        acc += g[(size_t)r * OUT_F + f];
    }
    float dc = dinv[node];
    out[(size_t)node * OUT_F + f] = (acc + g[(size_t)node * OUT_F + f]) * dc + b[f];
}

extern "C" void kernel_launch(void* const* d_in, const int* in_sizes, int n_in,
                              void* d_out, int out_size, void* d_ws, size_t ws_size,
                              hipStream_t stream) {
    const float* x  = (const float*)d_in[0];
    const int*   ei = (const int*)d_in[1];
    const float* W  = (const float*)d_in[2];
    const float* b  = (const float*)d_in[3];
    float* out = (float*)d_out;

    int n = in_sizes[0] / IN_F;
    int E = in_sizes[1] / 2;
    const int* rowp = ei;       // edge_index[0] = source
    const int* colp = ei + E;   // edge_index[1] = target

    // workspace layout
    float* g      = (float*)d_ws;                    // n*64 f32 = 25.6 MB (dinv-scaled xW)
    int*   bucket = (int*)(g + (size_t)n * OUT_F);   // E int   =  6.4 MB
    int*   deg    = bucket + E;                      // n int
    float* dinv   = (float*)(deg + n);               // n f32
    int*   start  = (int*)(dinv + n);                // n int
    int*   cursor = start + n;                       // n int
    int*   bsum   = cursor + n;                      // <=512 int

    int nb = (n + 255) / 256;   // scan blocks (391 for n=100000, fits scan2's 512)

    hipMemsetAsync(deg, 0, (size_t)n * sizeof(int), stream);
    count_deg_kernel<<<(E + 255) / 256, 256, 0, stream>>>(colp, deg, E);
    dinv_kernel<<<(n + 255) / 256, 256, 0, stream>>>(deg, dinv, n);
    scan1_kernel<<<nb, 256, 0, stream>>>(deg, start, bsum, n);
    scan2_kernel<<<1, 512, 0, stream>>>(bsum, nb);
    scan3_kernel<<<nb, 256, 0, stream>>>(start, cursor, bsum, n);
    bucket_kernel<<<(E + 255) / 256, 256, 0, stream>>>(rowp, colp, cursor, bucket, E);
    gemm_kernel<<<(n + GR - 1) / GR, 256, 0, stream>>>(x, W, dinv, g, n);
    gather_kernel<<<(n + 3) / 4, 256, 0, stream>>>(start, deg, bucket, g, dinv, b, out, n);
}

// Round 5
// 317.431 us; speedup vs baseline: 5.7279x; 1.1957x over previous
//
#include <hip/hip_runtime.h>

// GCNConv: out = D^-1/2 (A + I) D^-1/2 (x W) + b
// x: [N,256] f32, edge_index: [2,E] int, W: [256,64] f32, b: [64] f32
// out: [N,64] f32
//
// CSR-gather aggregation (range-partitioned bucket build for L2-local writes),
// LDS-staged fp32 GEMM (4x4 register tile) with dinv folded in, g stored bf16.

#define IN_F 256
#define OUT_F 64
#define GR 64            // gemm rows per block
#define XS_STRIDE 65     // row stride in float4s (64 data + 1 pad)
#define NPASS 4          // bucket build passes (col-range partitioned)

typedef unsigned short ushort_t;

static __device__ __forceinline__ ushort_t f2bf(float f) {
    unsigned u = __float_as_uint(f);
    unsigned r = (u + 0x7FFFu + ((u >> 16) & 1u)) >> 16;   // RNE
    return (ushort_t)r;
}
static __device__ __forceinline__ float bf2f(ushort_t h) {
    return __uint_as_float(((unsigned)h) << 16);
}

// --- deg[col[e]] += 1 (int) ---
__global__ void count_deg_kernel(const int* __restrict__ col, int* __restrict__ deg, int E) {
    int e = blockIdx.x * blockDim.x + threadIdx.x;
    if (e < E) atomicAdd(&deg[col[e]], 1);
}

// --- dinv[i] = rsqrt(deg[i] + 1)  (+1 = self loop) ---
__global__ void dinv_kernel(const int* __restrict__ deg, float* __restrict__ dinv, int n) {
    int i = blockIdx.x * blockDim.x + threadIdx.x;
    if (i < n) dinv[i] = rsqrtf((float)(deg[i] + 1));
}

// --- scan pass 1: block-local exclusive scan of deg into start; block sum -> bsum ---
__global__ void scan1_kernel(const int* __restrict__ deg, int* __restrict__ start,
                             int* __restrict__ bsum, int n) {
    __shared__ int lds[256];
    int tid = threadIdx.x;
    int i = blockIdx.x * 256 + tid;
    int v = (i < n) ? deg[i] : 0;
    lds[tid] = v;
    __syncthreads();
    for (int d = 1; d < 256; d <<= 1) {
        int t = (tid >= d) ? lds[tid - d] : 0;
        __syncthreads();
        lds[tid] += t;
        __syncthreads();
    }
    if (i < n) start[i] = lds[tid] - v;
    if (tid == 255) bsum[blockIdx.x] = lds[255];
}

// --- scan pass 2: exclusive scan of bsum (nb <= 512), single block ---
__global__ void scan2_kernel(int* __restrict__ bsum, int nb) {
    __shared__ int lds[512];
    int tid = threadIdx.x;
    int v = (tid < nb) ? bsum[tid] : 0;
    lds[tid] = v;
    __syncthreads();
    for (int d = 1; d < 512; d <<= 1) {
        int t = (tid >= d) ? lds[tid - d] : 0;
        __syncthreads();
        lds[tid] += t;
        __syncthreads();
    }
    if (tid < nb) bsum[tid] = lds[tid] - v;
}

// --- scan pass 3: start[i] += bsum[block]; cursor[i] = start[i] ---
__global__ void scan3_kernel(int* __restrict__ start, int* __restrict__ cursor,
                             const int* __restrict__ bsum, int n) {
    int i = blockIdx.x * 256 + threadIdx.x;
    if (i < n) {
        int s = start[i] + bsum[blockIdx.x];
        start[i] = s;
        cursor[i] = s;
    }
}

// --- bucket[pos] = row[e] for edges with col in [lo,hi) ---
__global__ void bucket_kernel(const int* __restrict__ row, const int* __restrict__ col,
                              int* __restrict__ cursor, int* __restrict__ bucket,
                              int E, int lo, int hi) {
    int e = blockIdx.x * blockDim.x + threadIdx.x;
    if (e < E) {
        int c = col[e];
        if (c >= lo && c < hi) {
            int pos = atomicAdd(&cursor[c], 1);
            bucket[pos] = row[e];
        }
    }
}

// --- g = bf16( dinv[r] * (x @ W)[r] ) : LDS x tile, 4 rows x 4 cols per thread ---
__global__ __launch_bounds__(256) void gemm_kernel(const float* __restrict__ x,
                                                   const float* __restrict__ W,
                                                   const float* __restrict__ dinv,
                                                   ushort_t* __restrict__ g, int n) {
    __shared__ float4 xs[GR * XS_STRIDE];   // 66560 B
    int tid = threadIdx.x;
    int row0 = blockIdx.x * GR;

    const float4* xg = (const float4*)x;
    #pragma unroll
    for (int i = 0; i < GR * (IN_F / 4) / 256; ++i) {   // 16 iters
        int idx = i * 256 + tid;
        int r = idx >> 6;          // 0..63
        int c = idx & 63;          // 0..63
        int grow = row0 + r;
        if (grow > n - 1) grow = n - 1;
        xs[r * XS_STRIDE + c] = xg[(size_t)grow * (IN_F / 4) + c];
    }
    __syncthreads();

    int tc = tid & 15;             // cols tc*4..tc*4+3
    int tr = tid >> 4;             // rows tr*4..tr*4+3
    const float4* Wv = (const float4*)W;
    const float4* a0 = &xs[(tr * 4 + 0) * XS_STRIDE];
    const float4* a1 = &xs[(tr * 4 + 1) * XS_STRIDE];
    const float4* a2 = &xs[(tr * 4 + 2) * XS_STRIDE];
    const float4* a3 = &xs[(tr * 4 + 3) * XS_STRIDE];

    float4 acc0 = make_float4(0.f, 0.f, 0.f, 0.f);
    float4 acc1 = make_float4(0.f, 0.f, 0.f, 0.f);
    float4 acc2 = make_float4(0.f, 0.f, 0.f, 0.f);
    float4 acc3 = make_float4(0.f, 0.f, 0.f, 0.f);

    #pragma unroll 2
    for (int k4 = 0; k4 < IN_F / 4; ++k4) {
        float4 w0 = Wv[(k4 * 4 + 0) * 16 + tc];
        float4 w1 = Wv[(k4 * 4 + 1) * 16 + tc];
        float4 w2 = Wv[(k4 * 4 + 2) * 16 + tc];
        float4 w3 = Wv[(k4 * 4 + 3) * 16 + tc];
        float4 v0 = a0[k4], v1 = a1[k4], v2 = a2[k4], v3 = a3[k4];
        acc0.x += v0.x * w0.x + v0.y * w1.x + v0.z * w2.x + v0.w * w3.x;
        acc0.y += v0.x * w0.y + v0.y * w1.y + v0.z * w2.y + v0.w * w3.y;
        acc0.z += v0.x * w0.z + v0.y * w1.z + v0.z * w2.z + v0.w * w3.z;
        acc0.w += v0.x * w0.w + v0.y * w1.w + v0.z * w2.w + v0.w * w3.w;
        acc1.x += v1.x * w0.x + v1.y * w1.x + v1.z * w2.x + v1.w * w3.x;
        acc1.y += v1.x * w0.y + v1.y * w1.y + v1.z * w2.y + v1.w * w3.y;
        acc1.z += v1.x * w0.z + v1.y * w1.z + v1.z * w2.z + v1.w * w3.z;
        acc1.w += v1.x * w0.w + v1.y * w1.w + v1.z * w2.w + v1.w * w3.w;
        acc2.x += v2.x * w0.x + v2.y * w1.x + v2.z * w2.x + v2.w * w3.x;
        acc2.y += v2.x * w0.y + v2.y * w1.y + v2.z * w2.y + v2.w * w3.y;
        acc2.z += v2.x * w0.z + v2.y * w1.z + v2.z * w2.z + v2.w * w3.z;
        acc2.w += v2.x * w0.w + v2.y * w1.w + v2.z * w2.w + v2.w * w3.w;
        acc3.x += v3.x * w0.x + v3.y * w1.x + v3.z * w2.x + v3.w * w3.x;
        acc3.y += v3.x * w0.y + v3.y * w1.y + v3.z * w2.y + v3.w * w3.y;
        acc3.z += v3.x * w0.z + v3.y * w1.z + v3.z * w2.z + v3.w * w3.z;
        acc3.w += v3.x * w0.w + v3.y * w1.w + v3.z * w2.w + v3.w * w3.w;
    }

    float4 accs[4] = {acc0, acc1, acc2, acc3};
    #pragma unroll
    for (int i = 0; i < 4; ++i) {
        int r = row0 + tr * 4 + i;
        if (r < n) {
            float d = dinv[r];
            float4 a = accs[i];
            ushort_t o0 = f2bf(a.x * d), o1 = f2bf(a.y * d),
                     o2 = f2bf(a.z * d), o3 = f2bf(a.w * d);
            ushort_t* dst = g + (size_t)r * OUT_F + tc * 4;
            *(ushort4*)dst = make_ushort4(o0, o1, o2, o3);
        }
    }
}

// --- out[c] = dinv[c] * (g[c] + sum_j g[bucket[j]]) + b ---
__global__ void gather_kernel(const int* __restrict__ start, const int* __restrict__ deg,
                              const int* __restrict__ bucket, const ushort_t* __restrict__ g,
                              const float* __restrict__ dinv, const float* __restrict__ b,
                              float* __restrict__ out, int n) {
    int node = blockIdx.x * 4 + (threadIdx.x >> 6);
    int f    = threadIdx.x & 63;
    if (node >= n) return;
    int s0  = start[node];
    int cnt = deg[node];
    float acc = 0.f;
    int j = 0;
    for (; j + 4 <= cnt; j += 4) {
        int r0 = bucket[s0 + j + 0];
        int r1 = bucket[s0 + j + 1];
        int r2 = bucket[s0 + j + 2];
        int r3 = bucket[s0 + j + 3];
        float v0 = bf2f(g[(size_t)r0 * OUT_F + f]);
        float v1 = bf2f(g[(size_t)r1 * OUT_F + f]);
        float v2 = bf2f(g[(size_t)r2 * OUT_F + f]);
        float v3 = bf2f(g[(size_t)r3 * OUT_F + f]);
        acc += v0 + v1 + v2 + v3;
    }
    for (; j < cnt; ++j) {
        int r = bucket[s0 + j];
        acc += bf2f(g[(size_t)r * OUT_F + f]);
    }
    float dc = dinv[node];
    out[(size_t)node * OUT_F + f] = (acc + bf2f(g[(size_t)node * OUT_F + f])) * dc + b[f];
}

extern "C" void kernel_launch(void* const* d_in, const int* in_sizes, int n_in,
                              void* d_out, int out_size, void* d_ws, size_t ws_size,
                              hipStream_t stream) {
    const float* x  = (const float*)d_in[0];
    const int*   ei = (const int*)d_in[1];
    const float* W  = (const float*)d_in[2];
    const float* b  = (const float*)d_in[3];
    float* out = (float*)d_out;

    int n = in_sizes[0] / IN_F;
    int E = in_sizes[1] / 2;
    const int* rowp = ei;       // edge_index[0] = source
    const int* colp = ei + E;   // edge_index[1] = target

    // workspace layout
    ushort_t* g    = (ushort_t*)d_ws;                    // n*64 bf16 = 12.8 MB
    int*   bucket  = (int*)(g + (size_t)n * OUT_F);      // E int    =  6.4 MB
    int*   deg     = bucket + E;                         // n int
    float* dinv    = (float*)(deg + n);                  // n f32
    int*   start   = (int*)(dinv + n);                   // n int
    int*   cursor  = start + n;                          // n int
    int*   bsum    = cursor + n;                         // <=512 int

    int nb = (n + 255) / 256;   // 391 for n=100000

    hipMemsetAsync(deg, 0, (size_t)n * sizeof(int), stream);
    count_deg_kernel<<<(E + 255) / 256, 256, 0, stream>>>(colp, deg, E);
    dinv_kernel<<<(n + 255) / 256, 256, 0, stream>>>(deg, dinv, n);
    scan1_kernel<<<nb, 256, 0, stream>>>(deg, start, bsum, n);
    scan2_kernel<<<1, 512, 0, stream>>>(bsum, nb);
    scan3_kernel<<<nb, 256, 0, stream>>>(start, cursor, bsum, n);
    for (int p = 0; p < NPASS; ++p) {
        int lo = (int)((long long)n * p / NPASS);
        int hi = (int)((long long)n * (p + 1) / NPASS);
        bucket_kernel<<<(E + 255) / 256, 256, 0, stream>>>(rowp, colp, cursor, bucket, E, lo, hi);
    }
    gemm_kernel<<<(n + GR - 1) / GR, 256, 0, stream>>>(x, W, dinv, g, n);
    gather_kernel<<<(n + 3) / 4, 256, 0, stream>>>(start, deg, bucket, g, dinv, b, out, n);
}

// Round 6
// 280.473 us; speedup vs baseline: 6.4826x; 1.1318x over previous
//
#include <hip/hip_runtime.h>

// GCNConv: out = D^-1/2 (A + I) D^-1/2 (x W) + b
// x: [N,256] f32, edge_index: [2,E] int, W: [256,64] f32, b: [64] f32
// out: [N,64] f32
//
// CSR-gather aggregation (2-pass range-partitioned bucket build),
// MFMA bf16 GEMM: x streamed直接 global->frag (no LDS), W pre-packed into
// fragment-ordered bf16 buffer; dinv folded into epilogue; g stored bf16.

#define IN_F 256
#define OUT_F 64
#define NPASS 2

typedef unsigned short ushort_t;
typedef short bf16x8 __attribute__((ext_vector_type(8)));
typedef float f32x4 __attribute__((ext_vector_type(4)));

static __device__ __forceinline__ unsigned f2bf1(float f) {
    unsigned u = __float_as_uint(f);
    return (u + 0x7FFFu + ((u >> 16) & 1u)) >> 16;   // RNE
}
static __device__ __forceinline__ unsigned pk2(float a, float b) {
    return f2bf1(a) | (f2bf1(b) << 16);
}
static __device__ __forceinline__ ushort_t f2bf(float f) { return (ushort_t)f2bf1(f); }
static __device__ __forceinline__ float bf2f(ushort_t h) {
    return __uint_as_float(((unsigned)h) << 16);
}

// --- deg[col[e]] += 1 (int) ---
__global__ void count_deg_kernel(const int* __restrict__ col, int* __restrict__ deg, int E) {
    int e = blockIdx.x * blockDim.x + threadIdx.x;
    if (e < E) atomicAdd(&deg[col[e]], 1);
}

// --- dinv[i] = rsqrt(deg[i] + 1)  (+1 = self loop) ---
__global__ void dinv_kernel(const int* __restrict__ deg, float* __restrict__ dinv, int n) {
    int i = blockIdx.x * blockDim.x + threadIdx.x;
    if (i < n) dinv[i] = rsqrtf((float)(deg[i] + 1));
}

// --- scan pass 1: block-local exclusive scan of deg into start; block sum -> bsum ---
__global__ void scan1_kernel(const int* __restrict__ deg, int* __restrict__ start,
                             int* __restrict__ bsum, int n) {
    __shared__ int lds[256];
    int tid = threadIdx.x;
    int i = blockIdx.x * 256 + tid;
    int v = (i < n) ? deg[i] : 0;
    lds[tid] = v;
    __syncthreads();
    for (int d = 1; d < 256; d <<= 1) {
        int t = (tid >= d) ? lds[tid - d] : 0;
        __syncthreads();
        lds[tid] += t;
        __syncthreads();
    }
    if (i < n) start[i] = lds[tid] - v;
    if (tid == 255) bsum[blockIdx.x] = lds[255];
}

// --- scan pass 2: exclusive scan of bsum (nb <= 512), single block ---
__global__ void scan2_kernel(int* __restrict__ bsum, int nb) {
    __shared__ int lds[512];
    int tid = threadIdx.x;
    int v = (tid < nb) ? bsum[tid] : 0;
    lds[tid] = v;
    __syncthreads();
    for (int d = 1; d < 512; d <<= 1) {
        int t = (tid >= d) ? lds[tid - d] : 0;
        __syncthreads();
        lds[tid] += t;
        __syncthreads();
    }
    if (tid < nb) bsum[tid] = lds[tid] - v;
}

// --- scan pass 3: start[i] += bsum[block]; cursor[i] = start[i] ---
__global__ void scan3_kernel(int* __restrict__ start, int* __restrict__ cursor,
                             const int* __restrict__ bsum, int n) {
    int i = blockIdx.x * 256 + threadIdx.x;
    if (i < n) {
        int s = start[i] + bsum[blockIdx.x];
        start[i] = s;
        cursor[i] = s;
    }
}

// --- bucket[pos] = row[e] for edges with col in [lo,hi) ---
__global__ void bucket_kernel(const int* __restrict__ row, const int* __restrict__ col,
                              int* __restrict__ cursor, int* __restrict__ bucket,
                              int E, int lo, int hi) {
    int e = blockIdx.x * blockDim.x + threadIdx.x;
    if (e < E) {
        int c = col[e];
        if (c >= lo && c < hi) {
            int pos = atomicAdd(&cursor[c], 1);
            bucket[pos] = row[e];
        }
    }
}

// --- pack W into fragment-ordered bf16: slot s=(kk*4+ct)*64+l holds
//     W[32kk+8*(l>>4)+j][16ct+(l&15)], j=0..7 (16B per slot) ---
__global__ void wfrag_kernel(const float* __restrict__ W, ushort_t* __restrict__ wfrag) {
    int t = blockIdx.x * 256 + threadIdx.x;   // 0..2047
    if (t >= 2048) return;
    int kk = t >> 8;
    int ct = (t >> 6) & 3;
    int l  = t & 63;
    int k0 = kk * 32 + (l >> 4) * 8;
    int c  = ct * 16 + (l & 15);
    unsigned u0 = pk2(W[(k0 + 0) * OUT_F + c], W[(k0 + 1) * OUT_F + c]);
    unsigned u1 = pk2(W[(k0 + 2) * OUT_F + c], W[(k0 + 3) * OUT_F + c]);
    unsigned u2 = pk2(W[(k0 + 4) * OUT_F + c], W[(k0 + 5) * OUT_F + c]);
    unsigned u3 = pk2(W[(k0 + 6) * OUT_F + c], W[(k0 + 7) * OUT_F + c]);
    ((uint4*)wfrag)[t] = make_uint4(u0, u1, u2, u3);
}

// --- g = bf16( dinv[r] * (x @ W)[r] ) via MFMA 16x16x32 bf16 ---
// Block = 256 threads = 4 waves; wave wm covers rows blk*64+wm*16..+15, all 64 cols.
__global__ __launch_bounds__(256) void gemm_kernel(const float* __restrict__ x,
                                                   const ushort_t* __restrict__ wfrag,
                                                   const float* __restrict__ dinv,
                                                   ushort_t* __restrict__ g, int n) {
    int tid = threadIdx.x;
    int l  = tid & 63;
    int lr = l & 15;       // A row within tile / D col within tile
    int lg = l >> 4;       // k-group / D row group
    int rowbase = blockIdx.x * 64 + (tid >> 6) * 16;
    int arow = rowbase + lr;
    int lrow = (arow < n) ? arow : (n - 1);           // clamp loads for tail
    const float* xp = x + (size_t)lrow * IN_F + lg * 8;
    const uint4* wf = (const uint4*)wfrag;

    f32x4 acc0 = {0.f, 0.f, 0.f, 0.f};
    f32x4 acc1 = {0.f, 0.f, 0.f, 0.f};
    f32x4 acc2 = {0.f, 0.f, 0.f, 0.f};
    f32x4 acc3 = {0.f, 0.f, 0.f, 0.f};

    #pragma unroll
    for (int kk = 0; kk < 8; ++kk) {
        float4 xa = *(const float4*)(xp + kk * 32);
        float4 xb = *(const float4*)(xp + kk * 32 + 4);
        union { bf16x8 v; unsigned u[4]; } A;
        A.u[0] = pk2(xa.x, xa.y);
        A.u[1] = pk2(xa.z, xa.w);
        A.u[2] = pk2(xb.x, xb.y);
        A.u[3] = pk2(xb.z, xb.w);
        union { uint4 q; bf16x8 v; } B0, B1, B2, B3;
        B0.q = wf[(kk * 4 + 0) * 64 + l];
        B1.q = wf[(kk * 4 + 1) * 64 + l];
        B2.q = wf[(kk * 4 + 2) * 64 + l];
        B3.q = wf[(kk * 4 + 3) * 64 + l];
        acc0 = __builtin_amdgcn_mfma_f32_16x16x32_bf16(A.v, B0.v, acc0, 0, 0, 0);
        acc1 = __builtin_amdgcn_mfma_f32_16x16x32_bf16(A.v, B1.v, acc1, 0, 0, 0);
        acc2 = __builtin_amdgcn_mfma_f32_16x16x32_bf16(A.v, B2.v, acc2, 0, 0, 0);
        acc3 = __builtin_amdgcn_mfma_f32_16x16x32_bf16(A.v, B3.v, acc3, 0, 0, 0);
    }

    // D layout: lane l, reg q -> row = 4*(l>>4)+q, col = l&15 (per 16x16 tile)
    #pragma unroll
    for (int q = 0; q < 4; ++q) {
        int r = rowbase + lg * 4 + q;
        if (r < n) {
            float dv = dinv[r];
            ushort_t* gp = g + (size_t)r * OUT_F + lr;
            gp[0]  = f2bf(acc0[q] * dv);
            gp[16] = f2bf(acc1[q] * dv);
            gp[32] = f2bf(acc2[q] * dv);
            gp[48] = f2bf(acc3[q] * dv);
        }
    }
}

// --- out[c] = dinv[c] * (g[c] + sum_j g[bucket[j]]) + b ---
__global__ void gather_kernel(const int* __restrict__ start, const int* __restrict__ deg,
                              const int* __restrict__ bucket, const ushort_t* __restrict__ g,
                              const float* __restrict__ dinv, const float* __restrict__ b,
                              float* __restrict__ out, int n) {
    int node = blockIdx.x * 4 + (threadIdx.x >> 6);
    int f    = threadIdx.x & 63;
    if (node >= n) return;
    int s0  = start[node];
    int cnt = deg[node];
    float acc = 0.f;
    int j = 0;
    for (; j + 4 <= cnt; j += 4) {
        int r0 = bucket[s0 + j + 0];
        int r1 = bucket[s0 + j + 1];
        int r2 = bucket[s0 + j + 2];
        int r3 = bucket[s0 + j + 3];
        float v0 = bf2f(g[(size_t)r0 * OUT_F + f]);
        float v1 = bf2f(g[(size_t)r1 * OUT_F + f]);
        float v2 = bf2f(g[(size_t)r2 * OUT_F + f]);
        float v3 = bf2f(g[(size_t)r3 * OUT_F + f]);
        acc += v0 + v1 + v2 + v3;
    }
    for (; j < cnt; ++j) {
        int r = bucket[s0 + j];
        acc += bf2f(g[(size_t)r * OUT_F + f]);
    }
    float dc = dinv[node];
    out[(size_t)node * OUT_F + f] = (acc + bf2f(g[(size_t)node * OUT_F + f])) * dc + b[f];
}

extern "C" void kernel_launch(void* const* d_in, const int* in_sizes, int n_in,
                              void* d_out, int out_size, void* d_ws, size_t ws_size,
                              hipStream_t stream) {
    const float* x  = (const float*)d_in[0];
    const int*   ei = (const int*)d_in[1];
    const float* W  = (const float*)d_in[2];
    const float* b  = (const float*)d_in[3];
    float* out = (float*)d_out;

    int n = in_sizes[0] / IN_F;
    int E = in_sizes[1] / 2;
    const int* rowp = ei;       // edge_index[0] = source
    const int* colp = ei + E;   // edge_index[1] = target

    // workspace layout
    ushort_t* g    = (ushort_t*)d_ws;                    // n*64 bf16 = 12.8 MB
    int*   bucket  = (int*)(g + (size_t)n * OUT_F);      // E int    =  6.4 MB
    int*   deg     = bucket + E;                         // n int
    float* dinv    = (float*)(deg + n);                  // n f32
    int*   start   = (int*)(dinv + n);                   // n int
    int*   cursor  = start + n;                          // n int
    int*   bsum    = cursor + n;                         // 512 int
    ushort_t* wfrag = (ushort_t*)(bsum + 512);           // 2048*8 ushort = 32 KB

    int nb = (n + 255) / 256;   // 391 for n=100000

    wfrag_kernel<<<8, 256, 0, stream>>>(W, wfrag);
    hipMemsetAsync(deg, 0, (size_t)n * sizeof(int), stream);
    count_deg_kernel<<<(E + 255) / 256, 256, 0, stream>>>(colp, deg, E);
    dinv_kernel<<<(n + 255) / 256, 256, 0, stream>>>(deg, dinv, n);
    scan1_kernel<<<nb, 256, 0, stream>>>(deg, start, bsum, n);
    scan2_kernel<<<1, 512, 0, stream>>>(bsum, nb);
    scan3_kernel<<<nb, 256, 0, stream>>>(start, cursor, bsum, n);
    for (int p = 0; p < NPASS; ++p) {
        int lo = (int)((long long)n * p / NPASS);
        int hi = (int)((long long)n * (p + 1) / NPASS);
        bucket_kernel<<<(E + 255) / 256, 256, 0, stream>>>(rowp, colp, cursor, bucket, E, lo, hi);
    }
    gemm_kernel<<<(n + 63) / 64, 256, 0, stream>>>(x, wfrag, dinv, g, n);
    gather_kernel<<<(n + 3) / 4, 256, 0, stream>>>(start, deg, bucket, g, dinv, b, out, n);
}

// Round 7
// 165.022 us; speedup vs baseline: 11.0180x; 1.6996x over previous
//
#include <hip/hip_runtime.h>

// GCNConv: out = D^-1/2 (A + I) D^-1/2 (x W) + b
// x: [N,256] f32, edge_index: [2,E] int, W: [256,64] f32, b: [64] f32
// out: [N,64] f32
//
// Two-level (radix-style) CSR build with LDS atomics (no mass global atomics),
// MFMA bf16 GEMM (x streamed global->frag, W pre-packed), dinv folded, g bf16.

#define IN_F 256
#define OUT_F 64
#define WBITS 8                  // fine window = 256 nodes per coarse bin
#define MAXBINS 512

typedef unsigned short ushort_t;
typedef short bf16x8 __attribute__((ext_vector_type(8)));
typedef float f32x4 __attribute__((ext_vector_type(4)));

static __device__ __forceinline__ unsigned f2bf1(float f) {
    unsigned u = __float_as_uint(f);
    return (u + 0x7FFFu + ((u >> 16) & 1u)) >> 16;   // RNE
}
static __device__ __forceinline__ unsigned pk2(float a, float b) {
    return f2bf1(a) | (f2bf1(b) << 16);
}
static __device__ __forceinline__ ushort_t f2bf(float f) { return (ushort_t)f2bf1(f); }
static __device__ __forceinline__ float bf2f(ushort_t h) {
    return __uint_as_float(((unsigned)h) << 16);
}

// --- pass A: coarse bin histogram (LDS), flush with few global atomics ---
__global__ __launch_bounds__(256) void bin_count_kernel(const int* __restrict__ col,
                                                        int* __restrict__ binCnt,
                                                        int E, int nbins) {
    __shared__ int hist[MAXBINS];
    int tid = threadIdx.x;
    for (int i = tid; i < nbins; i += 256) hist[i] = 0;
    __syncthreads();
    int stride = gridDim.x * 256;
    for (int e = blockIdx.x * 256 + tid; e < E; e += stride)
        atomicAdd(&hist[col[e] >> WBITS], 1);
    __syncthreads();
    for (int i = tid; i < nbins; i += 256)
        if (hist[i]) atomicAdd(&binCnt[i], hist[i]);
}

// --- pass B: exclusive scan of binCnt -> binStart, binCursor; start[n] = E ---
__global__ void bin_scan_kernel(const int* __restrict__ binCnt, int* __restrict__ binStart,
                                int* __restrict__ binCursor, int* __restrict__ start_n,
                                int nbins) {
    __shared__ int lds[512];
    int tid = threadIdx.x;   // 512 threads
    int v = (tid < nbins) ? binCnt[tid] : 0;
    lds[tid] = v;
    __syncthreads();
    for (int d = 1; d < 512; d <<= 1) {
        int t = (tid >= d) ? lds[tid - d] : 0;
        __syncthreads();
        lds[tid] += t;
        __syncthreads();
    }
    if (tid < nbins) {
        int ex = lds[tid] - v;
        binStart[tid] = ex;
        binCursor[tid] = ex;
    }
    if (tid == 511) {
        binStart[nbins] = lds[511];   // = E
        start_n[0] = lds[511];        // start[n] = E
    }
}

// --- pass C: scatter edges into coarse-bin-sorted ebuf (LDS cursors) ---
__global__ __launch_bounds__(256) void coarse_scatter_kernel(const int* __restrict__ row,
                                                             const int* __restrict__ col,
                                                             int* __restrict__ binCursor,
                                                             uint2* __restrict__ ebuf,
                                                             int E, int nbins) {
    __shared__ int cnt[MAXBINS];
    __shared__ int cur[MAXBINS];
    int tid = threadIdx.x;
    for (int i = tid; i < nbins; i += 256) cnt[i] = 0;
    __syncthreads();
    int chunk = (E + gridDim.x - 1) / gridDim.x;
    int s = blockIdx.x * chunk;
    int epos = min(E, s + chunk);
    for (int e = s + tid; e < epos; e += 256)
        atomicAdd(&cnt[col[e] >> WBITS], 1);
    __syncthreads();
    for (int i = tid; i < nbins; i += 256) {
        int c = cnt[i];
        cur[i] = c ? atomicAdd(&binCursor[i], c) : 0;
    }
    __syncthreads();
    for (int e = s + tid; e < epos; e += 256) {
        int cc = col[e];
        int pos = atomicAdd(&cur[cc >> WBITS], 1);
        ebuf[pos] = make_uint2((unsigned)row[e], (unsigned)cc);
    }
}

// --- pass D: per-bin fine CSR build, deg/dinv/start/bucket — all LDS-local ---
__global__ __launch_bounds__(256) void fine_build_kernel(const uint2* __restrict__ ebuf,
                                                         const int* __restrict__ binStart,
                                                         int* __restrict__ start,
                                                         float* __restrict__ dinv,
                                                         int* __restrict__ bucket, int n) {
    __shared__ int sdeg[256];
    __shared__ int scur[256];
    int b = blockIdx.x;
    int lo = b << WBITS;
    int wcnt = min(256, n - lo);
    int tid = threadIdx.x;
    sdeg[tid] = 0;
    __syncthreads();
    int s = binStart[b], epos = binStart[b + 1];
    for (int e = s + tid; e < epos; e += 256)
        atomicAdd(&sdeg[(int)ebuf[e].y - lo], 1);
    __syncthreads();
    int d = sdeg[tid];
    if (tid < wcnt) dinv[lo + tid] = rsqrtf((float)(d + 1));
    // Hillis-Steele inclusive scan over sdeg
    for (int dd = 1; dd < 256; dd <<= 1) {
        int t = (tid >= dd) ? sdeg[tid - dd] : 0;
        __syncthreads();
        sdeg[tid] += t;
        __syncthreads();
    }
    int ex = sdeg[tid] - d;
    if (tid < wcnt) start[lo + tid] = s + ex;
    scur[tid] = ex;
    __syncthreads();
    for (int e = s + tid; e < epos; e += 256) {
        uint2 pr = ebuf[e];
        int pos = atomicAdd(&scur[(int)pr.y - lo], 1);
        bucket[s + pos] = (int)pr.x;
    }
}

// --- pack W into fragment-ordered bf16 (B-frag for mfma 16x16x32) ---
__global__ void wfrag_kernel(const float* __restrict__ W, ushort_t* __restrict__ wfrag) {
    int t = blockIdx.x * 256 + threadIdx.x;   // 0..2047
    if (t >= 2048) return;
    int kk = t >> 8;
    int ct = (t >> 6) & 3;
    int l  = t & 63;
    int k0 = kk * 32 + (l >> 4) * 8;
    int c  = ct * 16 + (l & 15);
    unsigned u0 = pk2(W[(k0 + 0) * OUT_F + c], W[(k0 + 1) * OUT_F + c]);
    unsigned u1 = pk2(W[(k0 + 2) * OUT_F + c], W[(k0 + 3) * OUT_F + c]);
    unsigned u2 = pk2(W[(k0 + 4) * OUT_F + c], W[(k0 + 5) * OUT_F + c]);
    unsigned u3 = pk2(W[(k0 + 6) * OUT_F + c], W[(k0 + 7) * OUT_F + c]);
    ((uint4*)wfrag)[t] = make_uint4(u0, u1, u2, u3);
}

// --- g = bf16( dinv[r] * (x @ W)[r] ) via MFMA 16x16x32 bf16 ---
__global__ __launch_bounds__(256) void gemm_kernel(const float* __restrict__ x,
                                                   const ushort_t* __restrict__ wfrag,
                                                   const float* __restrict__ dinv,
                                                   ushort_t* __restrict__ g, int n) {
    int tid = threadIdx.x;
    int l  = tid & 63;
    int lr = l & 15;
    int lg = l >> 4;
    int rowbase = blockIdx.x * 64 + (tid >> 6) * 16;
    int arow = rowbase + lr;
    int lrow = (arow < n) ? arow : (n - 1);
    const float* xp = x + (size_t)lrow * IN_F + lg * 8;
    const uint4* wf = (const uint4*)wfrag;

    f32x4 acc0 = {0.f, 0.f, 0.f, 0.f};
    f32x4 acc1 = {0.f, 0.f, 0.f, 0.f};
    f32x4 acc2 = {0.f, 0.f, 0.f, 0.f};
    f32x4 acc3 = {0.f, 0.f, 0.f, 0.f};

    #pragma unroll
    for (int kk = 0; kk < 8; ++kk) {
        float4 xa = *(const float4*)(xp + kk * 32);
        float4 xb = *(const float4*)(xp + kk * 32 + 4);
        union { bf16x8 v; unsigned u[4]; } A;
        A.u[0] = pk2(xa.x, xa.y);
        A.u[1] = pk2(xa.z, xa.w);
        A.u[2] = pk2(xb.x, xb.y);
        A.u[3] = pk2(xb.z, xb.w);
        union { uint4 q; bf16x8 v; } B0, B1, B2, B3;
        B0.q = wf[(kk * 4 + 0) * 64 + l];
        B1.q = wf[(kk * 4 + 1) * 64 + l];
        B2.q = wf[(kk * 4 + 2) * 64 + l];
        B3.q = wf[(kk * 4 + 3) * 64 + l];
        acc0 = __builtin_amdgcn_mfma_f32_16x16x32_bf16(A.v, B0.v, acc0, 0, 0, 0);
        acc1 = __builtin_amdgcn_mfma_f32_16x16x32_bf16(A.v, B1.v, acc1, 0, 0, 0);
        acc2 = __builtin_amdgcn_mfma_f32_16x16x32_bf16(A.v, B2.v, acc2, 0, 0, 0);
        acc3 = __builtin_amdgcn_mfma_f32_16x16x32_bf16(A.v, B3.v, acc3, 0, 0, 0);
    }

    #pragma unroll
    for (int q = 0; q < 4; ++q) {
        int r = rowbase + lg * 4 + q;
        if (r < n) {
            float dv = dinv[r];
            ushort_t* gp = g + (size_t)r * OUT_F + lr;
            gp[0]  = f2bf(acc0[q] * dv);
            gp[16] = f2bf(acc1[q] * dv);
            gp[32] = f2bf(acc2[q] * dv);
            gp[48] = f2bf(acc3[q] * dv);
        }
    }
}

// --- out[c] = dinv[c] * (g[c] + sum_j g[bucket[j]]) + b ---
__global__ void gather_kernel(const int* __restrict__ start,
                              const int* __restrict__ bucket, const ushort_t* __restrict__ g,
                              const float* __restrict__ dinv, const float* __restrict__ b,
                              float* __restrict__ out, int n) {
    int node = blockIdx.x * 4 + (threadIdx.x >> 6);
    int f    = threadIdx.x & 63;
    if (node >= n) return;
    int s0  = start[node];
    int cnt = start[node + 1] - s0;
    float acc = 0.f;
    int j = 0;
    for (; j + 4 <= cnt; j += 4) {
        int r0 = bucket[s0 + j + 0];
        int r1 = bucket[s0 + j + 1];
        int r2 = bucket[s0 + j + 2];
        int r3 = bucket[s0 + j + 3];
        float v0 = bf2f(g[(size_t)r0 * OUT_F + f]);
        float v1 = bf2f(g[(size_t)r1 * OUT_F + f]);
        float v2 = bf2f(g[(size_t)r2 * OUT_F + f]);
        float v3 = bf2f(g[(size_t)r3 * OUT_F + f]);
        acc += v0 + v1 + v2 + v3;
    }
    for (; j < cnt; ++j) {
        int r = bucket[s0 + j];
        acc += bf2f(g[(size_t)r * OUT_F + f]);
    }
    float dc = dinv[node];
    out[(size_t)node * OUT_F + f] = (acc + bf2f(g[(size_t)node * OUT_F + f])) * dc + b[f];
}

extern "C" void kernel_launch(void* const* d_in, const int* in_sizes, int n_in,
                              void* d_out, int out_size, void* d_ws, size_t ws_size,
                              hipStream_t stream) {
    const float* x  = (const float*)d_in[0];
    const int*   ei = (const int*)d_in[1];
    const float* W  = (const float*)d_in[2];
    const float* b  = (const float*)d_in[3];
    float* out = (float*)d_out;

    int n = in_sizes[0] / IN_F;
    int E = in_sizes[1] / 2;
    const int* rowp = ei;       // edge_index[0] = source
    const int* colp = ei + E;   // edge_index[1] = target

    int nbins = (n + 255) >> WBITS;   // 391 for n=100000 (<= MAXBINS)

    // workspace layout (ebuf aliases g: ebuf consumed by fine_build before gemm writes g)
    char* wp = (char*)d_ws;
    ushort_t* g   = (ushort_t*)wp;                    // n*64 bf16 = 12.8 MB
    uint2* ebuf   = (uint2*)wp;                       // E uint2  = 12.8 MB (alias)
    size_t r0 = (size_t)E * 8;
    size_t r1 = (size_t)n * OUT_F * 2;
    size_t roff = (r0 > r1 ? r0 : r1);
    int* bucket   = (int*)(wp + roff);                // E int = 6.4 MB
    ushort_t* wfrag = (ushort_t*)(bucket + E);        // 32 KB (16B-aligned)
    int* start    = (int*)(wfrag + 16384);            // (n+1) int
    float* dinv   = (float*)(start + n + 1);          // n f32
    int* binCnt   = (int*)(dinv + n);                 // MAXBINS int
    int* binStart = binCnt + MAXBINS;                 // MAXBINS+1 int
    int* binCursor= binStart + MAXBINS + 1;           // MAXBINS int

    wfrag_kernel<<<8, 256, 0, stream>>>(W, wfrag);
    hipMemsetAsync(binCnt, 0, MAXBINS * sizeof(int), stream);
    bin_count_kernel<<<256, 256, 0, stream>>>(colp, binCnt, E, nbins);
    bin_scan_kernel<<<1, 512, 0, stream>>>(binCnt, binStart, binCursor, start + n, nbins);
    coarse_scatter_kernel<<<256, 256, 0, stream>>>(rowp, colp, binCursor, ebuf, E, nbins);
    fine_build_kernel<<<nbins, 256, 0, stream>>>(ebuf, binStart, start, dinv, bucket, n);
    gemm_kernel<<<(n + 63) / 64, 256, 0, stream>>>(x, wfrag, dinv, g, n);
    gather_kernel<<<(n + 3) / 4, 256, 0, stream>>>(start, bucket, g, dinv, b, out, n);
}

// Round 8
// 153.584 us; speedup vs baseline: 11.8385x; 1.0745x over previous
//
#include <hip/hip_runtime.h>

// GCNConv: out = D^-1/2 (A + I) D^-1/2 (x W) + b
// x: [N,256] f32, edge_index: [2,E] int, W: [256,64] f32, b: [64] f32
// out: [N,64] f32
//
// Two-level CSR build (LDS atomics, packed uint32 edge buffer),
// MFMA bf16 GEMM (x streamed global->frag, W pre-packed), dinv folded, g bf16,
// MLP-deep (unroll-8) gather.

#define IN_F 256
#define OUT_F 64
#define WBITS 8                  // fine window = 256 nodes per coarse bin
#define MAXBINS 512
#define ROWMASK 0xFFFFFFu        // n < 2^24

typedef unsigned short ushort_t;
typedef short bf16x8 __attribute__((ext_vector_type(8)));
typedef float f32x4 __attribute__((ext_vector_type(4)));

static __device__ __forceinline__ unsigned f2bf1(float f) {
    unsigned u = __float_as_uint(f);
    return (u + 0x7FFFu + ((u >> 16) & 1u)) >> 16;   // RNE
}
static __device__ __forceinline__ unsigned pk2(float a, float b) {
    return f2bf1(a) | (f2bf1(b) << 16);
}
static __device__ __forceinline__ ushort_t f2bf(float f) { return (ushort_t)f2bf1(f); }
static __device__ __forceinline__ float bf2f(ushort_t h) {
    return __uint_as_float(((unsigned)h) << 16);
}

// --- pass A: coarse bin histogram (LDS), flush with few global atomics ---
__global__ __launch_bounds__(256) void bin_count_kernel(const int* __restrict__ col,
                                                        int* __restrict__ binCnt,
                                                        int E, int nbins) {
    __shared__ int hist[MAXBINS];
    int tid = threadIdx.x;
    for (int i = tid; i < nbins; i += 256) hist[i] = 0;
    __syncthreads();
    int stride = gridDim.x * 256;
    for (int e = blockIdx.x * 256 + tid; e < E; e += stride)
        atomicAdd(&hist[col[e] >> WBITS], 1);
    __syncthreads();
    for (int i = tid; i < nbins; i += 256)
        if (hist[i]) atomicAdd(&binCnt[i], hist[i]);
}

// --- pass B: exclusive scan of binCnt -> binStart, binCursor; start[n] = E ---
__global__ void bin_scan_kernel(const int* __restrict__ binCnt, int* __restrict__ binStart,
                                int* __restrict__ binCursor, int* __restrict__ start_n,
                                int nbins) {
    __shared__ int lds[512];
    int tid = threadIdx.x;   // 512 threads
    int v = (tid < nbins) ? binCnt[tid] : 0;
    lds[tid] = v;
    __syncthreads();
    for (int d = 1; d < 512; d <<= 1) {
        int t = (tid >= d) ? lds[tid - d] : 0;
        __syncthreads();
        lds[tid] += t;
        __syncthreads();
    }
    if (tid < nbins) {
        int ex = lds[tid] - v;
        binStart[tid] = ex;
        binCursor[tid] = ex;
    }
    if (tid == 511) {
        binStart[nbins] = lds[511];   // = E
        start_n[0] = lds[511];        // start[n] = E
    }
}

// --- pass C: scatter edges into coarse-bin-sorted packed ebuf (LDS cursors) ---
// packed: u = row | (col_local << 24)
__global__ __launch_bounds__(256) void coarse_scatter_kernel(const int* __restrict__ row,
                                                             const int* __restrict__ col,
                                                             int* __restrict__ binCursor,
                                                             unsigned* __restrict__ ebuf,
                                                             int E, int nbins) {
    __shared__ int cnt[MAXBINS];
    __shared__ int cur[MAXBINS];
    int tid = threadIdx.x;
    for (int i = tid; i < nbins; i += 256) cnt[i] = 0;
    __syncthreads();
    int chunk = (E + gridDim.x - 1) / gridDim.x;
    int s = blockIdx.x * chunk;
    int epos = min(E, s + chunk);
    for (int e = s + tid; e < epos; e += 256)
        atomicAdd(&cnt[col[e] >> WBITS], 1);
    __syncthreads();
    for (int i = tid; i < nbins; i += 256) {
        int c = cnt[i];
        cur[i] = c ? atomicAdd(&binCursor[i], c) : 0;
    }
    __syncthreads();
    for (int e = s + tid; e < epos; e += 256) {
        int cc = col[e];
        int pos = atomicAdd(&cur[cc >> WBITS], 1);
        ebuf[pos] = (unsigned)row[e] | ((unsigned)(cc & ((1 << WBITS) - 1)) << 24);
    }
}

// --- pass D: per-bin fine CSR build, deg/dinv/start/bucket — all LDS-local ---
__global__ __launch_bounds__(256) void fine_build_kernel(const unsigned* __restrict__ ebuf,
                                                         const int* __restrict__ binStart,
                                                         int* __restrict__ start,
                                                         float* __restrict__ dinv,
                                                         int* __restrict__ bucket, int n) {
    __shared__ int sdeg[256];
    __shared__ int scur[256];
    int b = blockIdx.x;
    int lo = b << WBITS;
    int wcnt = min(256, n - lo);
    int tid = threadIdx.x;
    sdeg[tid] = 0;
    __syncthreads();
    int s = binStart[b], epos = binStart[b + 1];
    for (int e = s + tid; e < epos; e += 256)
        atomicAdd(&sdeg[ebuf[e] >> 24], 1);
    __syncthreads();
    int d = sdeg[tid];
    if (tid < wcnt) dinv[lo + tid] = rsqrtf((float)(d + 1));
    for (int dd = 1; dd < 256; dd <<= 1) {
        int t = (tid >= dd) ? sdeg[tid - dd] : 0;
        __syncthreads();
        sdeg[tid] += t;
        __syncthreads();
    }
    int ex = sdeg[tid] - d;
    if (tid < wcnt) start[lo + tid] = s + ex;
    scur[tid] = ex;
    __syncthreads();
    for (int e = s + tid; e < epos; e += 256) {
        unsigned pr = ebuf[e];
        int pos = atomicAdd(&scur[pr >> 24], 1);
        bucket[s + pos] = (int)(pr & ROWMASK);
    }
}

// --- pack W into fragment-ordered bf16 (B-frag for mfma 16x16x32) ---
__global__ void wfrag_kernel(const float* __restrict__ W, ushort_t* __restrict__ wfrag) {
    int t = blockIdx.x * 256 + threadIdx.x;   // 0..2047
    if (t >= 2048) return;
    int kk = t >> 8;
    int ct = (t >> 6) & 3;
    int l  = t & 63;
    int k0 = kk * 32 + (l >> 4) * 8;
    int c  = ct * 16 + (l & 15);
    unsigned u0 = pk2(W[(k0 + 0) * OUT_F + c], W[(k0 + 1) * OUT_F + c]);
    unsigned u1 = pk2(W[(k0 + 2) * OUT_F + c], W[(k0 + 3) * OUT_F + c]);
    unsigned u2 = pk2(W[(k0 + 4) * OUT_F + c], W[(k0 + 5) * OUT_F + c]);
    unsigned u3 = pk2(W[(k0 + 6) * OUT_F + c], W[(k0 + 7) * OUT_F + c]);
    ((uint4*)wfrag)[t] = make_uint4(u0, u1, u2, u3);
}

// --- g = bf16( dinv[r] * (x @ W)[r] ) via MFMA 16x16x32 bf16 ---
__global__ __launch_bounds__(256) void gemm_kernel(const float* __restrict__ x,
                                                   const ushort_t* __restrict__ wfrag,
                                                   const float* __restrict__ dinv,
                                                   ushort_t* __restrict__ g, int n) {
    int tid = threadIdx.x;
    int l  = tid & 63;
    int lr = l & 15;
    int lg = l >> 4;
    int rowbase = blockIdx.x * 64 + (tid >> 6) * 16;
    int arow = rowbase + lr;
    int lrow = (arow < n) ? arow : (n - 1);
    const float* xp = x + (size_t)lrow * IN_F + lg * 8;
    const uint4* wf = (const uint4*)wfrag;

    f32x4 acc0 = {0.f, 0.f, 0.f, 0.f};
    f32x4 acc1 = {0.f, 0.f, 0.f, 0.f};
    f32x4 acc2 = {0.f, 0.f, 0.f, 0.f};
    f32x4 acc3 = {0.f, 0.f, 0.f, 0.f};

    #pragma unroll
    for (int kk = 0; kk < 8; ++kk) {
        float4 xa = *(const float4*)(xp + kk * 32);
        float4 xb = *(const float4*)(xp + kk * 32 + 4);
        union { bf16x8 v; unsigned u[4]; } A;
        A.u[0] = pk2(xa.x, xa.y);
        A.u[1] = pk2(xa.z, xa.w);
        A.u[2] = pk2(xb.x, xb.y);
        A.u[3] = pk2(xb.z, xb.w);
        union { uint4 q; bf16x8 v; } B0, B1, B2, B3;
        B0.q = wf[(kk * 4 + 0) * 64 + l];
        B1.q = wf[(kk * 4 + 1) * 64 + l];
        B2.q = wf[(kk * 4 + 2) * 64 + l];
        B3.q = wf[(kk * 4 + 3) * 64 + l];
        acc0 = __builtin_amdgcn_mfma_f32_16x16x32_bf16(A.v, B0.v, acc0, 0, 0, 0);
        acc1 = __builtin_amdgcn_mfma_f32_16x16x32_bf16(A.v, B1.v, acc1, 0, 0, 0);
        acc2 = __builtin_amdgcn_mfma_f32_16x16x32_bf16(A.v, B2.v, acc2, 0, 0, 0);
        acc3 = __builtin_amdgcn_mfma_f32_16x16x32_bf16(A.v, B3.v, acc3, 0, 0, 0);
    }

    #pragma unroll
    for (int q = 0; q < 4; ++q) {
        int r = rowbase + lg * 4 + q;
        if (r < n) {
            float dv = dinv[r];
            ushort_t* gp = g + (size_t)r * OUT_F + lr;
            gp[0]  = f2bf(acc0[q] * dv);
            gp[16] = f2bf(acc1[q] * dv);
            gp[32] = f2bf(acc2[q] * dv);
            gp[48] = f2bf(acc3[q] * dv);
        }
    }
}

// --- out[c] = dinv[c] * (g[c] + sum_j g[bucket[j]]) + b, masked unroll-8 ---
__global__ __launch_bounds__(256) void gather_kernel(const int* __restrict__ start,
                              const int* __restrict__ bucket, const ushort_t* __restrict__ g,
                              const float* __restrict__ dinv, const float* __restrict__ b,
                              float* __restrict__ out, int n) {
    int node = blockIdx.x * 4 + (threadIdx.x >> 6);
    int f    = threadIdx.x & 63;
    if (node >= n) return;
    int s0  = start[node];
    int cnt = start[node + 1] - s0;
    const int* bp = bucket + s0;
    float self = bf2f(g[(size_t)node * OUT_F + f]);
    float acc0 = 0.f, acc1 = 0.f, acc2 = 0.f, acc3 = 0.f;
    int last = cnt - 1;
    for (int j = 0; j < cnt; j += 8) {
        int i0 = bp[min(j + 0, last)];
        int i1 = bp[min(j + 1, last)];
        int i2 = bp[min(j + 2, last)];
        int i3 = bp[min(j + 3, last)];
        int i4 = bp[min(j + 4, last)];
        int i5 = bp[min(j + 5, last)];
        int i6 = bp[min(j + 6, last)];
        int i7 = bp[min(j + 7, last)];
        float v0 = bf2f(g[(size_t)i0 * OUT_F + f]);
        float v1 = bf2f(g[(size_t)i1 * OUT_F + f]);
        float v2 = bf2f(g[(size_t)i2 * OUT_F + f]);
        float v3 = bf2f(g[(size_t)i3 * OUT_F + f]);
        float v4 = bf2f(g[(size_t)i4 * OUT_F + f]);
        float v5 = bf2f(g[(size_t)i5 * OUT_F + f]);
        float v6 = bf2f(g[(size_t)i6 * OUT_F + f]);
        float v7 = bf2f(g[(size_t)i7 * OUT_F + f]);
        acc0 += (j + 0 < cnt) ? v0 : 0.f;
        acc1 += (j + 1 < cnt) ? v1 : 0.f;
        acc2 += (j + 2 < cnt) ? v2 : 0.f;
        acc3 += (j + 3 < cnt) ? v3 : 0.f;
        acc0 += (j + 4 < cnt) ? v4 : 0.f;
        acc1 += (j + 5 < cnt) ? v5 : 0.f;
        acc2 += (j + 6 < cnt) ? v6 : 0.f;
        acc3 += (j + 7 < cnt) ? v7 : 0.f;
    }
    float acc = (acc0 + acc1) + (acc2 + acc3);
    float dc = dinv[node];
    out[(size_t)node * OUT_F + f] = (acc + self) * dc + b[f];
}

extern "C" void kernel_launch(void* const* d_in, const int* in_sizes, int n_in,
                              void* d_out, int out_size, void* d_ws, size_t ws_size,
                              hipStream_t stream) {
    const float* x  = (const float*)d_in[0];
    const int*   ei = (const int*)d_in[1];
    const float* W  = (const float*)d_in[2];
    const float* b  = (const float*)d_in[3];
    float* out = (float*)d_out;

    int n = in_sizes[0] / IN_F;
    int E = in_sizes[1] / 2;
    const int* rowp = ei;       // edge_index[0] = source
    const int* colp = ei + E;   // edge_index[1] = target

    int nbins = (n + 255) >> WBITS;   // 391 for n=100000 (<= MAXBINS)

    // workspace layout (ebuf aliases g: ebuf consumed by fine_build before gemm writes g)
    char* wp = (char*)d_ws;
    ushort_t* g   = (ushort_t*)wp;                    // n*64 bf16 = 12.8 MB
    unsigned* ebuf = (unsigned*)wp;                   // E uint32 = 6.4 MB (alias)
    size_t r0 = (size_t)E * 4;
    size_t r1 = (size_t)n * OUT_F * 2;
    size_t roff = (r0 > r1 ? r0 : r1);
    int* bucket   = (int*)(wp + roff);                // E int = 6.4 MB
    ushort_t* wfrag = (ushort_t*)(bucket + E);        // 32 KB (16B-aligned)
    int* start    = (int*)(wfrag + 16384);            // (n+1) int
    float* dinv   = (float*)(start + n + 1);          // n f32
    int* binCnt   = (int*)(dinv + n);                 // MAXBINS int
    int* binStart = binCnt + MAXBINS;                 // MAXBINS+1 int
    int* binCursor= binStart + MAXBINS + 1;           // MAXBINS int

    wfrag_kernel<<<8, 256, 0, stream>>>(W, wfrag);
    hipMemsetAsync(binCnt, 0, MAXBINS * sizeof(int), stream);
    bin_count_kernel<<<512, 256, 0, stream>>>(colp, binCnt, E, nbins);
    bin_scan_kernel<<<1, 512, 0, stream>>>(binCnt, binStart, binCursor, start + n, nbins);
    coarse_scatter_kernel<<<512, 256, 0, stream>>>(rowp, colp, binCursor, ebuf, E, nbins);
    fine_build_kernel<<<nbins, 256, 0, stream>>>(ebuf, binStart, start, dinv, bucket, n);
    gemm_kernel<<<(n + 63) / 64, 256, 0, stream>>>(x, wfrag, dinv, g, n);
    gather_kernel<<<(n + 3) / 4, 256, 0, stream>>>(start, bucket, g, dinv, b, out, n);
}

// Round 9
// 151.922 us; speedup vs baseline: 11.9680x; 1.0109x over previous
//
#include <hip/hip_runtime.h>

// GCNConv: out = D^-1/2 (A + I) D^-1/2 (x W) + b
// x: [N,256] f32, edge_index: [2,E] int, W: [256,64] f32, b: [64] f32
// out: [N,64] f32
//
// Two-level CSR build (LDS atomics, packed uint32 edge buffer),
// MFMA bf16 GEMM (x streamed global->frag, W pre-packed), dinv folded, g bf16,
// subgroup-parallel gather (4 edges in flight per VMEM issue, 16 deep).

#define IN_F 256
#define OUT_F 64
#define WBITS 8                  // fine window = 256 nodes per coarse bin
#define MAXBINS 512
#define ROWMASK 0xFFFFFFu        // n < 2^24

typedef unsigned short ushort_t;
typedef short bf16x8 __attribute__((ext_vector_type(8)));
typedef float f32x4 __attribute__((ext_vector_type(4)));

static __device__ __forceinline__ unsigned f2bf1(float f) {
    unsigned u = __float_as_uint(f);
    return (u + 0x7FFFu + ((u >> 16) & 1u)) >> 16;   // RNE
}
static __device__ __forceinline__ unsigned pk2(float a, float b) {
    return f2bf1(a) | (f2bf1(b) << 16);
}
static __device__ __forceinline__ ushort_t f2bf(float f) { return (ushort_t)f2bf1(f); }
static __device__ __forceinline__ float bf2f(ushort_t h) {
    return __uint_as_float(((unsigned)h) << 16);
}

// --- pass A: coarse bin histogram (LDS), flush with few global atomics ---
__global__ __launch_bounds__(256) void bin_count_kernel(const int* __restrict__ col,
                                                        int* __restrict__ binCnt,
                                                        int E, int nbins) {
    __shared__ int hist[MAXBINS];
    int tid = threadIdx.x;
    for (int i = tid; i < nbins; i += 256) hist[i] = 0;
    __syncthreads();
    int stride = gridDim.x * 256;
    for (int e = blockIdx.x * 256 + tid; e < E; e += stride)
        atomicAdd(&hist[col[e] >> WBITS], 1);
    __syncthreads();
    for (int i = tid; i < nbins; i += 256)
        if (hist[i]) atomicAdd(&binCnt[i], hist[i]);
}

// --- pass B: exclusive scan of binCnt -> binStart, binCursor; start[n] = E ---
__global__ void bin_scan_kernel(const int* __restrict__ binCnt, int* __restrict__ binStart,
                                int* __restrict__ binCursor, int* __restrict__ start_n,
                                int nbins) {
    __shared__ int lds[512];
    int tid = threadIdx.x;   // 512 threads
    int v = (tid < nbins) ? binCnt[tid] : 0;
    lds[tid] = v;
    __syncthreads();
    for (int d = 1; d < 512; d <<= 1) {
        int t = (tid >= d) ? lds[tid - d] : 0;
        __syncthreads();
        lds[tid] += t;
        __syncthreads();
    }
    if (tid < nbins) {
        int ex = lds[tid] - v;
        binStart[tid] = ex;
        binCursor[tid] = ex;
    }
    if (tid == 511) {
        binStart[nbins] = lds[511];   // = E
        start_n[0] = lds[511];        // start[n] = E
    }
}

// --- pass C: scatter edges into coarse-bin-sorted packed ebuf (LDS cursors) ---
// packed: u = row | (col_local << 24)
__global__ __launch_bounds__(256) void coarse_scatter_kernel(const int* __restrict__ row,
                                                             const int* __restrict__ col,
                                                             int* __restrict__ binCursor,
                                                             unsigned* __restrict__ ebuf,
                                                             int E, int nbins) {
    __shared__ int cnt[MAXBINS];
    __shared__ int cur[MAXBINS];
    int tid = threadIdx.x;
    for (int i = tid; i < nbins; i += 256) cnt[i] = 0;
    __syncthreads();
    int chunk = (E + gridDim.x - 1) / gridDim.x;
    int s = blockIdx.x * chunk;
    int epos = min(E, s + chunk);
    for (int e = s + tid; e < epos; e += 256)
        atomicAdd(&cnt[col[e] >> WBITS], 1);
    __syncthreads();
    for (int i = tid; i < nbins; i += 256) {
        int c = cnt[i];
        cur[i] = c ? atomicAdd(&binCursor[i], c) : 0;
    }
    __syncthreads();
    for (int e = s + tid; e < epos; e += 256) {
        int cc = col[e];
        int pos = atomicAdd(&cur[cc >> WBITS], 1);
        ebuf[pos] = (unsigned)row[e] | ((unsigned)(cc & ((1 << WBITS) - 1)) << 24);
    }
}

// --- pass D: per-bin fine CSR build, deg/dinv/start/bucket — all LDS-local ---
__global__ __launch_bounds__(256) void fine_build_kernel(const unsigned* __restrict__ ebuf,
                                                         const int* __restrict__ binStart,
                                                         int* __restrict__ start,
                                                         float* __restrict__ dinv,
                                                         int* __restrict__ bucket, int n) {
    __shared__ int sdeg[256];
    __shared__ int scur[256];
    int b = blockIdx.x;
    int lo = b << WBITS;
    int wcnt = min(256, n - lo);
    int tid = threadIdx.x;
    sdeg[tid] = 0;
    __syncthreads();
    int s = binStart[b], epos = binStart[b + 1];
    for (int e = s + tid; e < epos; e += 256)
        atomicAdd(&sdeg[ebuf[e] >> 24], 1);
    __syncthreads();
    int d = sdeg[tid];
    if (tid < wcnt) dinv[lo + tid] = rsqrtf((float)(d + 1));
    for (int dd = 1; dd < 256; dd <<= 1) {
        int t = (tid >= dd) ? sdeg[tid - dd] : 0;
        __syncthreads();
        sdeg[tid] += t;
        __syncthreads();
    }
    int ex = sdeg[tid] - d;
    if (tid < wcnt) start[lo + tid] = s + ex;
    scur[tid] = ex;
    __syncthreads();
    for (int e = s + tid; e < epos; e += 256) {
        unsigned pr = ebuf[e];
        int pos = atomicAdd(&scur[pr >> 24], 1);
        bucket[s + pos] = (int)(pr & ROWMASK);
    }
}

// --- pack W into fragment-ordered bf16 (B-frag for mfma 16x16x32) ---
__global__ void wfrag_kernel(const float* __restrict__ W, ushort_t* __restrict__ wfrag) {
    int t = blockIdx.x * 256 + threadIdx.x;   // 0..2047
    if (t >= 2048) return;
    int kk = t >> 8;
    int ct = (t >> 6) & 3;
    int l  = t & 63;
    int k0 = kk * 32 + (l >> 4) * 8;
    int c  = ct * 16 + (l & 15);
    unsigned u0 = pk2(W[(k0 + 0) * OUT_F + c], W[(k0 + 1) * OUT_F + c]);
    unsigned u1 = pk2(W[(k0 + 2) * OUT_F + c], W[(k0 + 3) * OUT_F + c]);
    unsigned u2 = pk2(W[(k0 + 4) * OUT_F + c], W[(k0 + 5) * OUT_F + c]);
    unsigned u3 = pk2(W[(k0 + 6) * OUT_F + c], W[(k0 + 7) * OUT_F + c]);
    ((uint4*)wfrag)[t] = make_uint4(u0, u1, u2, u3);
}

// --- g = bf16( dinv[r] * (x @ W)[r] ) via MFMA 16x16x32 bf16 ---
__global__ __launch_bounds__(256) void gemm_kernel(const float* __restrict__ x,
                                                   const ushort_t* __restrict__ wfrag,
                                                   const float* __restrict__ dinv,
                                                   ushort_t* __restrict__ g, int n) {
    int tid = threadIdx.x;
    int l  = tid & 63;
    int lr = l & 15;
    int lg = l >> 4;
    int rowbase = blockIdx.x * 64 + (tid >> 6) * 16;
    int arow = rowbase + lr;
    int lrow = (arow < n) ? arow : (n - 1);
    const float* xp = x + (size_t)lrow * IN_F + lg * 8;
    const uint4* wf = (const uint4*)wfrag;

    f32x4 acc0 = {0.f, 0.f, 0.f, 0.f};
    f32x4 acc1 = {0.f, 0.f, 0.f, 0.f};
    f32x4 acc2 = {0.f, 0.f, 0.f, 0.f};
    f32x4 acc3 = {0.f, 0.f, 0.f, 0.f};

    #pragma unroll
    for (int kk = 0; kk < 8; ++kk) {
        float4 xa = *(const float4*)(xp + kk * 32);
        float4 xb = *(const float4*)(xp + kk * 32 + 4);
        union { bf16x8 v; unsigned u[4]; } A;
        A.u[0] = pk2(xa.x, xa.y);
        A.u[1] = pk2(xa.z, xa.w);
        A.u[2] = pk2(xb.x, xb.y);
        A.u[3] = pk2(xb.z, xb.w);
        union { uint4 q; bf16x8 v; } B0, B1, B2, B3;
        B0.q = wf[(kk * 4 + 0) * 64 + l];
        B1.q = wf[(kk * 4 + 1) * 64 + l];
        B2.q = wf[(kk * 4 + 2) * 64 + l];
        B3.q = wf[(kk * 4 + 3) * 64 + l];
        acc0 = __builtin_amdgcn_mfma_f32_16x16x32_bf16(A.v, B0.v, acc0, 0, 0, 0);
        acc1 = __builtin_amdgcn_mfma_f32_16x16x32_bf16(A.v, B1.v, acc1, 0, 0, 0);
        acc2 = __builtin_amdgcn_mfma_f32_16x16x32_bf16(A.v, B2.v, acc2, 0, 0, 0);
        acc3 = __builtin_amdgcn_mfma_f32_16x16x32_bf16(A.v, B3.v, acc3, 0, 0, 0);
    }

    #pragma unroll
    for (int q = 0; q < 4; ++q) {
        int r = rowbase + lg * 4 + q;
        if (r < n) {
            float dv = dinv[r];
            ushort_t* gp = g + (size_t)r * OUT_F + lr;
            gp[0]  = f2bf(acc0[q] * dv);
            gp[16] = f2bf(acc1[q] * dv);
            gp[32] = f2bf(acc2[q] * dv);
            gp[48] = f2bf(acc3[q] * dv);
        }
    }
}

// --- out[c] = dinv[c] * (g[c] + sum_j g[bucket[j]]) + b ---
// Wave = 1 node; 4 subgroups of 16 lanes each walk different edges; lane holds
// 4 features (8 B). One VMEM issue fetches 4 edge-rows; unroll-4 => 16 in flight.
__global__ __launch_bounds__(256) void gather_kernel(const int* __restrict__ start,
                              const int* __restrict__ bucket, const ushort_t* __restrict__ g,
                              const float* __restrict__ dinv, const float* __restrict__ b,
                              float* __restrict__ out, int n) {
    int lane = threadIdx.x & 63;
    int node = blockIdx.x * 4 + (threadIdx.x >> 6);
    if (node >= n) return;
    int f4  = lane & 15;        // features 4*f4 .. 4*f4+3
    int grp = lane >> 4;        // edge subgroup 0..3
    int s0  = start[node];
    int cnt = start[node + 1] - s0;
    const int* bp = bucket + s0;
    int last = cnt - 1;

    float4 aA = {0,0,0,0}, aB = {0,0,0,0}, aC = {0,0,0,0}, aD = {0,0,0,0};
    for (int e0 = 0; e0 < cnt; e0 += 16) {
        int eA = e0 + grp;
        int eB = e0 + 4 + grp;
        int eC = e0 + 8 + grp;
        int eD = e0 + 12 + grp;
        int iA = bp[min(eA, last)];
        int iB = bp[min(eB, last)];
        int iC = bp[min(eC, last)];
        int iD = bp[min(eD, last)];
        ushort4 vA = *(const ushort4*)(g + (size_t)iA * OUT_F + f4 * 4);
        ushort4 vB = *(const ushort4*)(g + (size_t)iB * OUT_F + f4 * 4);
        ushort4 vC = *(const ushort4*)(g + (size_t)iC * OUT_F + f4 * 4);
        ushort4 vD = *(const ushort4*)(g + (size_t)iD * OUT_F + f4 * 4);
        aA.x += (eA < cnt) ? bf2f(vA.x) : 0.f;
        aA.y += (eA < cnt) ? bf2f(vA.y) : 0.f;
        aA.z += (eA < cnt) ? bf2f(vA.z) : 0.f;
        aA.w += (eA < cnt) ? bf2f(vA.w) : 0.f;
        aB.x += (eB < cnt) ? bf2f(vB.x) : 0.f;
        aB.y += (eB < cnt) ? bf2f(vB.y) : 0.f;
        aB.z += (eB < cnt) ? bf2f(vB.z) : 0.f;
        aB.w += (eB < cnt) ? bf2f(vB.w) : 0.f;
        aC.x += (eC < cnt) ? bf2f(vC.x) : 0.f;
        aC.y += (eC < cnt) ? bf2f(vC.y) : 0.f;
        aC.z += (eC < cnt) ? bf2f(vC.z) : 0.f;
        aC.w += (eC < cnt) ? bf2f(vC.w) : 0.f;
        aD.x += (eD < cnt) ? bf2f(vD.x) : 0.f;
        aD.y += (eD < cnt) ? bf2f(vD.y) : 0.f;
        aD.z += (eD < cnt) ? bf2f(vD.z) : 0.f;
        aD.w += (eD < cnt) ? bf2f(vD.w) : 0.f;
    }
    float4 acc;
    acc.x = (aA.x + aB.x) + (aC.x + aD.x);
    acc.y = (aA.y + aB.y) + (aC.y + aD.y);
    acc.z = (aA.z + aB.z) + (aC.z + aD.z);
    acc.w = (aA.w + aB.w) + (aC.w + aD.w);
    // cross-subgroup reduce (lanes l, l+16, l+32, l+48 hold same features)
    acc.x += __shfl_xor(acc.x, 16, 64);
    acc.y += __shfl_xor(acc.y, 16, 64);
    acc.z += __shfl_xor(acc.z, 16, 64);
    acc.w += __shfl_xor(acc.w, 16, 64);
    acc.x += __shfl_xor(acc.x, 32, 64);
    acc.y += __shfl_xor(acc.y, 32, 64);
    acc.z += __shfl_xor(acc.z, 32, 64);
    acc.w += __shfl_xor(acc.w, 32, 64);

    if (grp == 0) {
        ushort4 sv = *(const ushort4*)(g + (size_t)node * OUT_F + f4 * 4);
        float dc = dinv[node];
        float4 bv = ((const float4*)b)[f4];
        float4 o;
        o.x = (acc.x + bf2f(sv.x)) * dc + bv.x;
        o.y = (acc.y + bf2f(sv.y)) * dc + bv.y;
        o.z = (acc.z + bf2f(sv.z)) * dc + bv.z;
        o.w = (acc.w + bf2f(sv.w)) * dc + bv.w;
        ((float4*)(out + (size_t)node * OUT_F))[f4] = o;
    }
}

extern "C" void kernel_launch(void* const* d_in, const int* in_sizes, int n_in,
                              void* d_out, int out_size, void* d_ws, size_t ws_size,
                              hipStream_t stream) {
    const float* x  = (const float*)d_in[0];
    const int*   ei = (const int*)d_in[1];
    const float* W  = (const float*)d_in[2];
    const float* b  = (const float*)d_in[3];
    float* out = (float*)d_out;

    int n = in_sizes[0] / IN_F;
    int E = in_sizes[1] / 2;
    const int* rowp = ei;       // edge_index[0] = source
    const int* colp = ei + E;   // edge_index[1] = target

    int nbins = (n + 255) >> WBITS;   // 391 for n=100000 (<= MAXBINS)

    // workspace layout (ebuf aliases g: ebuf consumed by fine_build before gemm writes g)
    char* wp = (char*)d_ws;
    ushort_t* g   = (ushort_t*)wp;                    // n*64 bf16 = 12.8 MB
    unsigned* ebuf = (unsigned*)wp;                   // E uint32 = 6.4 MB (alias)
    size_t r0 = (size_t)E * 4;
    size_t r1 = (size_t)n * OUT_F * 2;
    size_t roff = (r0 > r1 ? r0 : r1);
    int* bucket   = (int*)(wp + roff);                // E int = 6.4 MB
    ushort_t* wfrag = (ushort_t*)(bucket + E);        // 32 KB (16B-aligned)
    int* start    = (int*)(wfrag + 16384);            // (n+1) int
    float* dinv   = (float*)(start + n + 1);          // n f32
    int* binCnt   = (int*)(dinv + n);                 // MAXBINS int
    int* binStart = binCnt + MAXBINS;                 // MAXBINS+1 int
    int* binCursor= binStart + MAXBINS + 1;           // MAXBINS int

    wfrag_kernel<<<8, 256, 0, stream>>>(W, wfrag);
    hipMemsetAsync(binCnt, 0, MAXBINS * sizeof(int), stream);
    bin_count_kernel<<<512, 256, 0, stream>>>(colp, binCnt, E, nbins);
    bin_scan_kernel<<<1, 512, 0, stream>>>(binCnt, binStart, binCursor, start + n, nbins);
    coarse_scatter_kernel<<<512, 256, 0, stream>>>(rowp, colp, binCursor, ebuf, E, nbins);
    fine_build_kernel<<<nbins, 256, 0, stream>>>(ebuf, binStart, start, dinv, bucket, n);
    gemm_kernel<<<(n + 63) / 64, 256, 0, stream>>>(x, wfrag, dinv, g, n);
    gather_kernel<<<(n + 3) / 4, 256, 0, stream>>>(start, bucket, g, dinv, b, out, n);
}

// Round 10
// 151.646 us; speedup vs baseline: 11.9898x; 1.0018x over previous
//
#include <hip/hip_runtime.h>

// GCNConv: out = D^-1/2 (A + I) D^-1/2 (x W) + b
// x: [N,256] f32, edge_index: [2,E] int, W: [256,64] f32, b: [64] f32
// out: [N,64] f32
//
// Two-level CSR build (LDS atomics, packed uint32 edge buffer) with the
// coarse scatter OVERLAPPED with the MFMA GEMM in one mega kernel;
// dinv scaling folded into fine_build; subgroup-parallel gather.

#define IN_F 256
#define OUT_F 64
#define WBITS 8                  // fine window = 256 nodes per coarse bin
#define MAXBINS 512
#define ROWMASK 0xFFFFFFu        // n < 2^24
#define SCAT_BLOCKS 512

typedef unsigned short ushort_t;
typedef short bf16x8 __attribute__((ext_vector_type(8)));
typedef float f32x4 __attribute__((ext_vector_type(4)));

static __device__ __forceinline__ unsigned f2bf1(float f) {
    unsigned u = __float_as_uint(f);
    return (u + 0x7FFFu + ((u >> 16) & 1u)) >> 16;   // RNE
}
static __device__ __forceinline__ unsigned pk2(float a, float b) {
    return f2bf1(a) | (f2bf1(b) << 16);
}
static __device__ __forceinline__ ushort_t f2bf(float f) { return (ushort_t)f2bf1(f); }
static __device__ __forceinline__ float bf2f(ushort_t h) {
    return __uint_as_float(((unsigned)h) << 16);
}

// --- K1: wfrag pack (blocks 0-7) + coarse bin histogram (all blocks) ---
__global__ __launch_bounds__(256) void init_kernel(const float* __restrict__ W,
                                                   ushort_t* __restrict__ wfrag,
                                                   const int* __restrict__ col,
                                                   int* __restrict__ binCnt,
                                                   int E, int nbins) {
    int gt = blockIdx.x * 256 + threadIdx.x;
    if (gt < 2048) {   // W fragment pack: slot t=(kk*4+ct)*64+l
        int t = gt;
        int kk = t >> 8;
        int ct = (t >> 6) & 3;
        int l  = t & 63;
        int k0 = kk * 32 + (l >> 4) * 8;
        int c  = ct * 16 + (l & 15);
        unsigned u0 = pk2(W[(k0 + 0) * OUT_F + c], W[(k0 + 1) * OUT_F + c]);
        unsigned u1 = pk2(W[(k0 + 2) * OUT_F + c], W[(k0 + 3) * OUT_F + c]);
        unsigned u2 = pk2(W[(k0 + 4) * OUT_F + c], W[(k0 + 5) * OUT_F + c]);
        unsigned u3 = pk2(W[(k0 + 6) * OUT_F + c], W[(k0 + 7) * OUT_F + c]);
        ((uint4*)wfrag)[t] = make_uint4(u0, u1, u2, u3);
    }
    __shared__ int hist[MAXBINS];
    int tid = threadIdx.x;
    for (int i = tid; i < nbins; i += 256) hist[i] = 0;
    __syncthreads();
    int stride = gridDim.x * 256;
    for (int e = blockIdx.x * 256 + tid; e < E; e += stride)
        atomicAdd(&hist[col[e] >> WBITS], 1);
    __syncthreads();
    for (int i = tid; i < nbins; i += 256)
        if (hist[i]) atomicAdd(&binCnt[i], hist[i]);
}

// --- K2: exclusive scan of binCnt -> binStart, binCursor; start[n] = E ---
__global__ void bin_scan_kernel(const int* __restrict__ binCnt, int* __restrict__ binStart,
                                int* __restrict__ binCursor, int* __restrict__ start_n,
                                int nbins) {
    __shared__ int lds[512];
    int tid = threadIdx.x;   // 512 threads
    int v = (tid < nbins) ? binCnt[tid] : 0;
    lds[tid] = v;
    __syncthreads();
    for (int d = 1; d < 512; d <<= 1) {
        int t = (tid >= d) ? lds[tid - d] : 0;
        __syncthreads();
        lds[tid] += t;
        __syncthreads();
    }
    if (tid < nbins) {
        int ex = lds[tid] - v;
        binStart[tid] = ex;
        binCursor[tid] = ex;
    }
    if (tid == 511) {
        binStart[nbins] = lds[511];   // = E
        start_n[0] = lds[511];        // start[n] = E
    }
}

// --- K3 MEGA: blocks [0,gemmBlocks) = MFMA GEMM h=xW (bf16, unscaled);
//              blocks [gemmBlocks, +SCAT_BLOCKS) = coarse scatter ---
__global__ __launch_bounds__(256) void mega_kernel(const float* __restrict__ x,
                                                   const ushort_t* __restrict__ wfrag,
                                                   ushort_t* __restrict__ h,
                                                   const int* __restrict__ row,
                                                   const int* __restrict__ col,
                                                   int* __restrict__ binCursor,
                                                   unsigned* __restrict__ ebuf,
                                                   int n, int E, int nbins, int gemmBlocks) {
    __shared__ int cnt[MAXBINS];
    __shared__ int cur[MAXBINS];
    int tid = threadIdx.x;

    if (blockIdx.x < gemmBlocks) {
        // ---------------- GEMM path ----------------
        int l  = tid & 63;
        int lr = l & 15;
        int lg = l >> 4;
        int rowbase = blockIdx.x * 64 + (tid >> 6) * 16;
        int arow = rowbase + lr;
        int lrow = (arow < n) ? arow : (n - 1);
        const float* xp = x + (size_t)lrow * IN_F + lg * 8;
        const uint4* wf = (const uint4*)wfrag;

        f32x4 acc0 = {0.f, 0.f, 0.f, 0.f};
        f32x4 acc1 = {0.f, 0.f, 0.f, 0.f};
        f32x4 acc2 = {0.f, 0.f, 0.f, 0.f};
        f32x4 acc3 = {0.f, 0.f, 0.f, 0.f};

        #pragma unroll
        for (int kk = 0; kk < 8; ++kk) {
            float4 xa = *(const float4*)(xp + kk * 32);
            float4 xb = *(const float4*)(xp + kk * 32 + 4);
            union { bf16x8 v; unsigned u[4]; } A;
            A.u[0] = pk2(xa.x, xa.y);
            A.u[1] = pk2(xa.z, xa.w);
            A.u[2] = pk2(xb.x, xb.y);
            A.u[3] = pk2(xb.z, xb.w);
            union { uint4 q; bf16x8 v; } B0, B1, B2, B3;
            B0.q = wf[(kk * 4 + 0) * 64 + l];
            B1.q = wf[(kk * 4 + 1) * 64 + l];
            B2.q = wf[(kk * 4 + 2) * 64 + l];
            B3.q = wf[(kk * 4 + 3) * 64 + l];
            acc0 = __builtin_amdgcn_mfma_f32_16x16x32_bf16(A.v, B0.v, acc0, 0, 0, 0);
            acc1 = __builtin_amdgcn_mfma_f32_16x16x32_bf16(A.v, B1.v, acc1, 0, 0, 0);
            acc2 = __builtin_amdgcn_mfma_f32_16x16x32_bf16(A.v, B2.v, acc2, 0, 0, 0);
            acc3 = __builtin_amdgcn_mfma_f32_16x16x32_bf16(A.v, B3.v, acc3, 0, 0, 0);
        }

        #pragma unroll
        for (int q = 0; q < 4; ++q) {
            int r = rowbase + lg * 4 + q;
            if (r < n) {
                ushort_t* gp = h + (size_t)r * OUT_F + lr;
                gp[0]  = f2bf(acc0[q]);
                gp[16] = f2bf(acc1[q]);
                gp[32] = f2bf(acc2[q]);
                gp[48] = f2bf(acc3[q]);
            }
        }
    } else {
        // ---------------- coarse scatter path ----------------
        int sb = blockIdx.x - gemmBlocks;   // 0..SCAT_BLOCKS-1
        for (int i = tid; i < nbins; i += 256) cnt[i] = 0;
        __syncthreads();
        int chunk = (E + SCAT_BLOCKS - 1) / SCAT_BLOCKS;
        int s = sb * chunk;
        int epos = min(E, s + chunk);
        for (int e = s + tid; e < epos; e += 256)
            atomicAdd(&cnt[col[e] >> WBITS], 1);
        __syncthreads();
        for (int i = tid; i < nbins; i += 256) {
            int c = cnt[i];
            cur[i] = c ? atomicAdd(&binCursor[i], c) : 0;
        }
        __syncthreads();
        for (int e = s + tid; e < epos; e += 256) {
            int cc = col[e];
            int pos = atomicAdd(&cur[cc >> WBITS], 1);
            ebuf[pos] = (unsigned)row[e] | ((unsigned)(cc & ((1 << WBITS) - 1)) << 24);
        }
    }
}

// --- K4: per-bin fine CSR build + in-place dinv scaling of g window ---
__global__ __launch_bounds__(256) void fine_build_kernel(const unsigned* __restrict__ ebuf,
                                                         const int* __restrict__ binStart,
                                                         int* __restrict__ start,
                                                         float* __restrict__ dinv,
                                                         int* __restrict__ bucket,
                                                         ushort_t* __restrict__ g, int n) {
    __shared__ int sdeg[256];
    __shared__ int scur[256];
    __shared__ float sdv[256];
    int b = blockIdx.x;
    int lo = b << WBITS;
    int wcnt = min(256, n - lo);
    int tid = threadIdx.x;
    sdeg[tid] = 0;
    __syncthreads();
    int s = binStart[b], epos = binStart[b + 1];
    for (int e = s + tid; e < epos; e += 256)
        atomicAdd(&sdeg[ebuf[e] >> 24], 1);
    __syncthreads();
    int d = sdeg[tid];
    float dv = rsqrtf((float)(d + 1));
    sdv[tid] = dv;
    if (tid < wcnt) dinv[lo + tid] = dv;
    for (int dd = 1; dd < 256; dd <<= 1) {
        int t = (tid >= dd) ? sdeg[tid - dd] : 0;
        __syncthreads();
        sdeg[tid] += t;
        __syncthreads();
    }
    int ex = sdeg[tid] - d;
    if (tid < wcnt) start[lo + tid] = s + ex;
    scur[tid] = ex;
    __syncthreads();
    for (int e = s + tid; e < epos; e += 256) {
        unsigned pr = ebuf[e];
        int pos = atomicAdd(&scur[pr >> 24], 1);
        bucket[s + pos] = (int)(pr & ROWMASK);
    }
    // scale g rows in this window: g[r] *= dinv[r] (bf16 in-place)
    unsigned* gw = (unsigned*)(g + (size_t)lo * OUT_F);
    int total = wcnt * 32;   // uints (2 bf16 each)
    for (int idx = tid; idx < total; idx += 256) {
        unsigned u = gw[idx];
        float sc = sdv[idx >> 5];
        float a = bf2f((ushort_t)(u & 0xFFFF)) * sc;
        float c = bf2f((ushort_t)(u >> 16)) * sc;
        gw[idx] = pk2(a, c);
    }
}

// --- K5: out[c] = dinv[c] * (g[c] + sum_j g[bucket[j]]) + b ---
// Wave = 1 node; 4 subgroups of 16 lanes each walk different edges; lane holds
// 4 features (8 B). One VMEM issue fetches 4 edge-rows; unroll-4 => 16 in flight.
__global__ __launch_bounds__(256) void gather_kernel(const int* __restrict__ start,
                              const int* __restrict__ bucket, const ushort_t* __restrict__ g,
                              const float* __restrict__ dinv, const float* __restrict__ b,
                              float* __restrict__ out, int n) {
    int lane = threadIdx.x & 63;
    int node = blockIdx.x * 4 + (threadIdx.x >> 6);
    if (node >= n) return;
    int f4  = lane & 15;        // features 4*f4 .. 4*f4+3
    int grp = lane >> 4;        // edge subgroup 0..3
    int s0  = start[node];
    int cnt = start[node + 1] - s0;
    const int* bp = bucket + s0;
    int last = cnt - 1;

    float4 aA = {0,0,0,0}, aB = {0,0,0,0}, aC = {0,0,0,0}, aD = {0,0,0,0};
    for (int e0 = 0; e0 < cnt; e0 += 16) {
        int eA = e0 + grp;
        int eB = e0 + 4 + grp;
        int eC = e0 + 8 + grp;
        int eD = e0 + 12 + grp;
        int iA = bp[min(eA, last)];
        int iB = bp[min(eB, last)];
        int iC = bp[min(eC, last)];
        int iD = bp[min(eD, last)];
        ushort4 vA = *(const ushort4*)(g + (size_t)iA * OUT_F + f4 * 4);
        ushort4 vB = *(const ushort4*)(g + (size_t)iB * OUT_F + f4 * 4);
        ushort4 vC = *(const ushort4*)(g + (size_t)iC * OUT_F + f4 * 4);
        ushort4 vD = *(const ushort4*)(g + (size_t)iD * OUT_F + f4 * 4);
        aA.x += (eA < cnt) ? bf2f(vA.x) : 0.f;
        aA.y += (eA < cnt) ? bf2f(vA.y) : 0.f;
        aA.z += (eA < cnt) ? bf2f(vA.z) : 0.f;
        aA.w += (eA < cnt) ? bf2f(vA.w) : 0.f;
        aB.x += (eB < cnt) ? bf2f(vB.x) : 0.f;
        aB.y += (eB < cnt) ? bf2f(vB.y) : 0.f;
        aB.z += (eB < cnt) ? bf2f(vB.z) : 0.f;
        aB.w += (eB < cnt) ? bf2f(vB.w) : 0.f;
        aC.x += (eC < cnt) ? bf2f(vC.x) : 0.f;
        aC.y += (eC < cnt) ? bf2f(vC.y) : 0.f;
        aC.z += (eC < cnt) ? bf2f(vC.z) : 0.f;
        aC.w += (eC < cnt) ? bf2f(vC.w) : 0.f;
        aD.x += (eD < cnt) ? bf2f(vD.x) : 0.f;
        aD.y += (eD < cnt) ? bf2f(vD.y) : 0.f;
        aD.z += (eD < cnt) ? bf2f(vD.z) : 0.f;
        aD.w += (eD < cnt) ? bf2f(vD.w) : 0.f;
    }
    float4 acc;
    acc.x = (aA.x + aB.x) + (aC.x + aD.x);
    acc.y = (aA.y + aB.y) + (aC.y + aD.y);
    acc.z = (aA.z + aB.z) + (aC.z + aD.z);
    acc.w = (aA.w + aB.w) + (aC.w + aD.w);
    acc.x += __shfl_xor(acc.x, 16, 64);
    acc.y += __shfl_xor(acc.y, 16, 64);
    acc.z += __shfl_xor(acc.z, 16, 64);
    acc.w += __shfl_xor(acc.w, 16, 64);
    acc.x += __shfl_xor(acc.x, 32, 64);
    acc.y += __shfl_xor(acc.y, 32, 64);
    acc.z += __shfl_xor(acc.z, 32, 64);
    acc.w += __shfl_xor(acc.w, 32, 64);

    if (grp == 0) {
        ushort4 sv = *(const ushort4*)(g + (size_t)node * OUT_F + f4 * 4);
        float dc = dinv[node];
        float4 bv = ((const float4*)b)[f4];
        float4 o;
        o.x = (acc.x + bf2f(sv.x)) * dc + bv.x;
        o.y = (acc.y + bf2f(sv.y)) * dc + bv.y;
        o.z = (acc.z + bf2f(sv.z)) * dc + bv.z;
        o.w = (acc.w + bf2f(sv.w)) * dc + bv.w;
        ((float4*)(out + (size_t)node * OUT_F))[f4] = o;
    }
}

extern "C" void kernel_launch(void* const* d_in, const int* in_sizes, int n_in,
                              void* d_out, int out_size, void* d_ws, size_t ws_size,
                              hipStream_t stream) {
    const float* x  = (const float*)d_in[0];
    const int*   ei = (const int*)d_in[1];
    const float* W  = (const float*)d_in[2];
    const float* b  = (const float*)d_in[3];
    float* out = (float*)d_out;

    int n = in_sizes[0] / IN_F;
    int E = in_sizes[1] / 2;
    const int* rowp = ei;       // edge_index[0] = source
    const int* colp = ei + E;   // edge_index[1] = target

    int nbins = (n + 255) >> WBITS;   // 391 for n=100000 (<= MAXBINS)

    // workspace layout (no aliasing: ebuf is live concurrently with g writes)
    char* wp = (char*)d_ws;
    ushort_t* g    = (ushort_t*)wp;                   // n*64 bf16 = 12.8 MB
    unsigned* ebuf = (unsigned*)(wp + (size_t)n * OUT_F * 2);   // E uint32 = 6.4 MB
    int* bucket    = (int*)(ebuf + E);                // E int = 6.4 MB
    ushort_t* wfrag = (ushort_t*)(bucket + E);        // 32 KB (16B-aligned)
    int* start     = (int*)(wfrag + 16384);           // (n+1) int
    float* dinv    = (float*)(start + n + 1);         // n f32
    int* binCnt    = (int*)(dinv + n);                // MAXBINS int
    int* binStart  = binCnt + MAXBINS;                // MAXBINS+1 int
    int* binCursor = binStart + MAXBINS + 1;          // MAXBINS int

    int gemmBlocks = (n + 63) / 64;

    hipMemsetAsync(binCnt, 0, MAXBINS * sizeof(int), stream);
    init_kernel<<<512, 256, 0, stream>>>(W, wfrag, colp, binCnt, E, nbins);
    bin_scan_kernel<<<1, 512, 0, stream>>>(binCnt, binStart, binCursor, start + n, nbins);
    mega_kernel<<<gemmBlocks + SCAT_BLOCKS, 256, 0, stream>>>(x, wfrag, g, rowp, colp,
                                                              binCursor, ebuf, n, E, nbins,
                                                              gemmBlocks);
    fine_build_kernel<<<nbins, 256, 0, stream>>>(ebuf, binStart, start, dinv, bucket, g, n);
    gather_kernel<<<(n + 3) / 4, 256, 0, stream>>>(start, bucket, g, dinv, b, out, n);
}